// Round 2
// baseline (830.190 us; speedup 1.0000x reference)
//
#include <hip/hip_runtime.h>

// ---------------- CSR build ----------------

__global__ void k_zero(int* __restrict__ p, int n) {
  for (int i = blockIdx.x * blockDim.x + threadIdx.x; i < n; i += gridDim.x * blockDim.x)
    p[i] = 0;
}

__global__ void k_count(const int* __restrict__ dst, int* __restrict__ cnt, int E) {
  for (int i = blockIdx.x * blockDim.x + threadIdx.x; i < E; i += gridDim.x * blockDim.x)
    atomicAdd(&cnt[dst[i]], 1);
}

// per-block exclusive scan of 1024 elements + block totals
__global__ void k_scan_local(const int* __restrict__ cnt, int* __restrict__ offs,
                             int* __restrict__ blockSums, int n) {
  __shared__ int wsum[16];
  __shared__ int wpre[16];
  int tid = threadIdx.x;
  int gid = blockIdx.x * 1024 + tid;
  int v = (gid < n) ? cnt[gid] : 0;
  int lane = tid & 63, wv = tid >> 6;
  int x = v;
#pragma unroll
  for (int d = 1; d < 64; d <<= 1) {
    int t = __shfl_up(x, d);
    if (lane >= d) x += t;
  }
  if (lane == 63) wsum[wv] = x;
  __syncthreads();
  if (tid == 0) {
    int run = 0;
#pragma unroll
    for (int i = 0; i < 16; ++i) { wpre[i] = run; run += wsum[i]; }
    blockSums[blockIdx.x] = run;
  }
  __syncthreads();
  if (gid < n) offs[gid] = x - v + wpre[wv];  // exclusive within block
}

__global__ void k_scan_blocks(const int* __restrict__ blockSums, int* __restrict__ blockOffs, int nb) {
  if (threadIdx.x == 0 && blockIdx.x == 0) {
    int run = 0;
    for (int i = 0; i < nb; ++i) { blockOffs[i] = run; run += blockSums[i]; }
    blockOffs[nb] = run;
  }
}

__global__ void k_scan_add(int* __restrict__ offs, const int* __restrict__ blockOffs,
                           const int* __restrict__ cnt, float* __restrict__ inv_sqrt,
                           int* __restrict__ next, int n) {
  int gid = blockIdx.x * 1024 + threadIdx.x;
  if (gid < n) {
    int o = offs[gid] + blockOffs[blockIdx.x];
    offs[gid] = o;
    next[gid] = o;
    inv_sqrt[gid] = rsqrtf(1.0f + (float)cnt[gid]);
  }
  if (gid == 0) offs[n] = blockOffs[gridDim.x];  // total E
}

__global__ void k_fill(const int* __restrict__ src, const int* __restrict__ dst,
                       const float* __restrict__ inv_sqrt, int* __restrict__ next,
                       int* __restrict__ srcs, float* __restrict__ coefs, int E) {
  for (int i = blockIdx.x * blockDim.x + threadIdx.x; i < E; i += gridDim.x * blockDim.x) {
    int s = src[i], d = dst[i];
    int pos = atomicAdd(&next[d], 1);
    srcs[pos] = s;
    coefs[pos] = inv_sqrt[s] * inv_sqrt[d];
  }
}

// ---------------- layer kernels ----------------

// aggregate 5-dim input: xagg = A_norm @ x   (lanes cooperate over edges, reduce)
__global__ void k_agg5(const float* __restrict__ x, const int* __restrict__ offs,
                       const int* __restrict__ srcs, const float* __restrict__ coefs,
                       const float* __restrict__ inv_sqrt, float* __restrict__ xagg, int n) {
  int wid = (blockIdx.x * blockDim.x + threadIdx.x) >> 6;
  int lane = threadIdx.x & 63;
  if (wid >= n) return;
  int beg = offs[wid], end = offs[wid + 1];
  float a0 = 0.f, a1 = 0.f, a2 = 0.f, a3 = 0.f, a4 = 0.f;
  for (int j = beg + lane; j < end; j += 64) {
    int s = srcs[j];
    float c = coefs[j];
    const float* xs = x + (size_t)s * 5;
    a0 = fmaf(xs[0], c, a0); a1 = fmaf(xs[1], c, a1); a2 = fmaf(xs[2], c, a2);
    a3 = fmaf(xs[3], c, a3); a4 = fmaf(xs[4], c, a4);
  }
#pragma unroll
  for (int d = 32; d; d >>= 1) {
    a0 += __shfl_xor(a0, d); a1 += __shfl_xor(a1, d); a2 += __shfl_xor(a2, d);
    a3 += __shfl_xor(a3, d); a4 += __shfl_xor(a4, d);
  }
  if (lane == 0) {
    float is = inv_sqrt[wid];
    float sc = is * is;
    const float* xi = x + (size_t)wid * 5;
    float* o = xagg + (size_t)wid * 5;
    o[0] = a0 + xi[0] * sc; o[1] = a1 + xi[1] * sc; o[2] = a2 + xi[2] * sc;
    o[3] = a3 + xi[3] * sc; o[4] = a4 + xi[4] * sc;
  }
}

// h1 = relu(xagg @ W1 + b1)   (wave per node, lane = output feature)
__global__ void k_l1(const float* __restrict__ xagg, const float* __restrict__ W1,
                     const float* __restrict__ b1, float* __restrict__ h, int n) {
  __shared__ float w[320];
  __shared__ float bsh[64];
  int tid = threadIdx.x;
  // BUGFIX: block is 256 threads but W1 has 320 elems — strided load.
  for (int i = tid; i < 320; i += 256) w[i] = W1[i];
  if (tid < 64) bsh[tid] = b1[tid];
  __syncthreads();
  int wid = (blockIdx.x * blockDim.x + tid) >> 6;
  int lane = tid & 63;
  if (wid >= n) return;
  const float* xi = xagg + (size_t)wid * 5;
  float acc = bsh[lane];
#pragma unroll
  for (int k = 0; k < 5; ++k) acc = fmaf(xi[k], w[k * 64 + lane], acc);
  h[(size_t)wid * 64 + lane] = fmaxf(acc, 0.f);
}

// h2raw = h1 @ W2  (wave-strided over nodes; W2 column in registers; shfl-broadcast row)
__global__ void k_hw2(const float* __restrict__ hin, const float* __restrict__ W2,
                      float* __restrict__ hout, int n) {
  int lane = threadIdx.x & 63;
  float wreg[64];
#pragma unroll
  for (int k = 0; k < 64; ++k) wreg[k] = W2[k * 64 + lane];
  int wid = (blockIdx.x * blockDim.x + threadIdx.x) >> 6;
  int nw = (gridDim.x * blockDim.x) >> 6;
  for (int i = wid; i < n; i += nw) {
    float hv = hin[(size_t)i * 64 + lane];
    float acc0 = 0.f, acc1 = 0.f, acc2 = 0.f, acc3 = 0.f;
#pragma unroll
    for (int k = 0; k < 64; k += 4) {
      acc0 = fmaf(__shfl(hv, k),     wreg[k],     acc0);
      acc1 = fmaf(__shfl(hv, k + 1), wreg[k + 1], acc1);
      acc2 = fmaf(__shfl(hv, k + 2), wreg[k + 2], acc2);
      acc3 = fmaf(__shfl(hv, k + 3), wreg[k + 3], acc3);
    }
    hout[(size_t)i * 64 + lane] = (acc0 + acc1) + (acc2 + acc3);
  }
}

// 64-dim aggregation: hout = relu(A_norm @ hraw + b)  (wave per node, lane = feature)
template <bool RELU>
__global__ void k_agg64(const float* __restrict__ hraw, const int* __restrict__ offs,
                        const int* __restrict__ srcs, const float* __restrict__ coefs,
                        const float* __restrict__ inv_sqrt, const float* __restrict__ bias,
                        float* __restrict__ hout, int n) {
  int wid = (blockIdx.x * blockDim.x + threadIdx.x) >> 6;
  int lane = threadIdx.x & 63;
  if (wid >= n) return;
  int beg = offs[wid], end = offs[wid + 1];
  float is = inv_sqrt[wid];
  float acc = hraw[(size_t)wid * 64 + lane] * (is * is);
  for (int j = beg; j < end; ++j) {
    int s = srcs[j];       // wave-uniform, cache-broadcast
    float c = coefs[j];
    acc = fmaf(hraw[(size_t)s * 64 + lane], c, acc);
  }
  acc += bias[lane];
  if (RELU) acc = fmaxf(acc, 0.f);
  hout[(size_t)wid * 64 + lane] = acc;
}

// h3 = h2 @ W3  (64 -> 2; wave per node, lane = k, shfl reduce)
__global__ void k_hw3(const float* __restrict__ hin, const float* __restrict__ W3,
                      float* __restrict__ h3, int n) {
  int lane = threadIdx.x & 63;
  float w0 = W3[lane * 2], w1 = W3[lane * 2 + 1];
  int wid = (blockIdx.x * blockDim.x + threadIdx.x) >> 6;
  int nw = (gridDim.x * blockDim.x) >> 6;
  for (int i = wid; i < n; i += nw) {
    float hv = hin[(size_t)i * 64 + lane];
    float a0 = hv * w0, a1 = hv * w1;
#pragma unroll
    for (int d = 32; d; d >>= 1) { a0 += __shfl_xor(a0, d); a1 += __shfl_xor(a1, d); }
    if (lane == 0) { h3[(size_t)i * 2] = a0; h3[(size_t)i * 2 + 1] = a1; }
  }
}

// out = A_norm @ h3 + self + b3  (wave per node, lanes cooperate over edges)
__global__ void k_agg2(const float* __restrict__ h3, const int* __restrict__ offs,
                       const int* __restrict__ srcs, const float* __restrict__ coefs,
                       const float* __restrict__ inv_sqrt, const float* __restrict__ b3,
                       float* __restrict__ out, int n) {
  int wid = (blockIdx.x * blockDim.x + threadIdx.x) >> 6;
  int lane = threadIdx.x & 63;
  if (wid >= n) return;
  int beg = offs[wid], end = offs[wid + 1];
  float a0 = 0.f, a1 = 0.f;
  for (int j = beg + lane; j < end; j += 64) {
    int s = srcs[j];
    float c = coefs[j];
    a0 = fmaf(h3[(size_t)s * 2], c, a0);
    a1 = fmaf(h3[(size_t)s * 2 + 1], c, a1);
  }
#pragma unroll
  for (int d = 32; d; d >>= 1) { a0 += __shfl_xor(a0, d); a1 += __shfl_xor(a1, d); }
  if (lane == 0) {
    float is = inv_sqrt[wid];
    float sc = is * is;
    out[(size_t)wid * 2]     = a0 + h3[(size_t)wid * 2] * sc + b3[0];
    out[(size_t)wid * 2 + 1] = a1 + h3[(size_t)wid * 2 + 1] * sc + b3[1];
  }
}

// ---------------- launcher ----------------

extern "C" void kernel_launch(void* const* d_in, const int* in_sizes, int n_in,
                              void* d_out, int out_size, void* d_ws, size_t ws_size,
                              hipStream_t stream) {
  const float* x  = (const float*)d_in[0];
  const int*   ei = (const int*)d_in[1];
  const float* W1 = (const float*)d_in[2];
  const float* b1 = (const float*)d_in[3];
  const float* W2 = (const float*)d_in[4];
  const float* b2 = (const float*)d_in[5];
  const float* W3 = (const float*)d_in[6];
  const float* b3 = (const float*)d_in[7];
  float* out = (float*)d_out;

  const int N = in_sizes[0] / 5;
  const int E = in_sizes[1] / 2;
  const int* src = ei;
  const int* dst = ei + E;

  char* p = (char*)d_ws;
  auto alloc = [&](size_t bytes) {
    char* r = p;
    p += (bytes + 255) & ~(size_t)255;
    return r;
  };
  const int nb = (N + 1023) / 1024;
  float* inv_sqrt  = (float*)alloc((size_t)N * 4);
  int*   cnt       = (int*)alloc((size_t)N * 4);
  int*   offs      = (int*)alloc((size_t)(N + 1) * 4);
  int*   nxt       = (int*)alloc((size_t)N * 4);
  int*   blockSums = (int*)alloc((size_t)nb * 4);
  int*   blockOffs = (int*)alloc((size_t)(nb + 1) * 4);
  int*   srcs      = (int*)alloc((size_t)E * 4);
  float* coefs     = (float*)alloc((size_t)E * 4);
  float* xagg      = (float*)alloc((size_t)N * 5 * 4);
  float* h3        = (float*)alloc((size_t)N * 2 * 4);
  float* hA        = (float*)alloc((size_t)N * 64 * 4);
  float* hB        = (float*)alloc((size_t)N * 64 * 4);

  const int wavesBlocks = (N * 64 + 255) / 256;  // one wave per node

  k_zero<<<512, 256, 0, stream>>>(cnt, N);
  k_count<<<2048, 256, 0, stream>>>(dst, cnt, E);
  k_scan_local<<<nb, 1024, 0, stream>>>(cnt, offs, blockSums, N);
  k_scan_blocks<<<1, 64, 0, stream>>>(blockSums, blockOffs, nb);
  k_scan_add<<<nb, 1024, 0, stream>>>(offs, blockOffs, cnt, inv_sqrt, nxt, N);
  k_fill<<<2048, 256, 0, stream>>>(src, dst, inv_sqrt, nxt, srcs, coefs, E);

  // layer 1: aggregate 5-dim x, then project+bias+relu
  k_agg5<<<wavesBlocks, 256, 0, stream>>>(x, offs, srcs, coefs, inv_sqrt, xagg, N);
  k_l1<<<wavesBlocks, 256, 0, stream>>>(xagg, W1, b1, hA, N);

  // layer 2: project 64->64, aggregate 64-dim with bias+relu
  k_hw2<<<2048, 256, 0, stream>>>(hA, W2, hB, N);
  k_agg64<true><<<wavesBlocks, 256, 0, stream>>>(hB, offs, srcs, coefs, inv_sqrt, b2, hA, N);

  // layer 3: project 64->2, aggregate 2-dim with bias
  k_hw3<<<2048, 256, 0, stream>>>(hA, W3, h3, N);
  k_agg2<<<wavesBlocks, 256, 0, stream>>>(h3, offs, srcs, coefs, inv_sqrt, b3, out, N);
}

// Round 3
// 724.419 us; speedup vs baseline: 1.1460x; 1.1460x over previous
//
#include <hip/hip_runtime.h>

// ---------------- CSR build ----------------

__global__ void k_zero(int* __restrict__ p, int n) {
  for (int i = blockIdx.x * blockDim.x + threadIdx.x; i < n; i += gridDim.x * blockDim.x)
    p[i] = 0;
}

__global__ void k_count(const int* __restrict__ dst, int* __restrict__ cnt, int E) {
  for (int i = blockIdx.x * blockDim.x + threadIdx.x; i < E; i += gridDim.x * blockDim.x)
    atomicAdd(&cnt[dst[i]], 1);
}

// per-block exclusive scan of 1024 elements + block totals
__global__ void k_scan_local(const int* __restrict__ cnt, int* __restrict__ offs,
                             int* __restrict__ blockSums, int n) {
  __shared__ int wsum[16];
  __shared__ int wpre[16];
  int tid = threadIdx.x;
  int gid = blockIdx.x * 1024 + tid;
  int v = (gid < n) ? cnt[gid] : 0;
  int lane = tid & 63, wv = tid >> 6;
  int x = v;
#pragma unroll
  for (int d = 1; d < 64; d <<= 1) {
    int t = __shfl_up(x, d);
    if (lane >= d) x += t;
  }
  if (lane == 63) wsum[wv] = x;
  __syncthreads();
  if (tid == 0) {
    int run = 0;
#pragma unroll
    for (int i = 0; i < 16; ++i) { wpre[i] = run; run += wsum[i]; }
    blockSums[blockIdx.x] = run;
  }
  __syncthreads();
  if (gid < n) offs[gid] = x - v + wpre[wv];  // exclusive within block
}

__global__ void k_scan_blocks(const int* __restrict__ blockSums, int* __restrict__ blockOffs, int nb) {
  if (threadIdx.x == 0 && blockIdx.x == 0) {
    int run = 0;
    for (int i = 0; i < nb; ++i) { blockOffs[i] = run; run += blockSums[i]; }
    blockOffs[nb] = run;
  }
}

__global__ void k_scan_add(int* __restrict__ offs, const int* __restrict__ blockOffs,
                           const int* __restrict__ cnt, float* __restrict__ inv_sqrt,
                           int* __restrict__ next, int n) {
  int gid = blockIdx.x * 1024 + threadIdx.x;
  if (gid < n) {
    int o = offs[gid] + blockOffs[blockIdx.x];
    offs[gid] = o;
    next[gid] = o;
    inv_sqrt[gid] = rsqrtf(1.0f + (float)cnt[gid]);
  }
  if (gid == 0) offs[n] = blockOffs[gridDim.x];  // total E
}

// srcs-only fill: coefs recomputed in agg kernels from L2-resident inv_sqrt
__global__ void k_fill(const int* __restrict__ src, const int* __restrict__ dst,
                       int* __restrict__ next, int* __restrict__ srcs, int E) {
  for (int i = blockIdx.x * blockDim.x + threadIdx.x; i < E; i += gridDim.x * blockDim.x) {
    int s = src[i], d = dst[i];
    int pos = atomicAdd(&next[d], 1);
    srcs[pos] = s;
  }
}

// ---------------- layer kernels ----------------

// aggregate 5-dim input: xagg = A_norm @ x   (lanes cooperate over edges, reduce)
__global__ void k_agg5(const float* __restrict__ x, const int* __restrict__ offs,
                       const int* __restrict__ srcs, const float* __restrict__ inv_sqrt,
                       float* __restrict__ xagg, int n) {
  int wid = (blockIdx.x * blockDim.x + threadIdx.x) >> 6;
  int lane = threadIdx.x & 63;
  if (wid >= n) return;
  int beg = offs[wid], end = offs[wid + 1];
  float isd = inv_sqrt[wid];
  float a0 = 0.f, a1 = 0.f, a2 = 0.f, a3 = 0.f, a4 = 0.f;
  for (int j = beg + lane; j < end; j += 64) {
    int s = srcs[j];
    float c = inv_sqrt[s] * isd;
    const float* xs = x + (size_t)s * 5;
    a0 = fmaf(xs[0], c, a0); a1 = fmaf(xs[1], c, a1); a2 = fmaf(xs[2], c, a2);
    a3 = fmaf(xs[3], c, a3); a4 = fmaf(xs[4], c, a4);
  }
#pragma unroll
  for (int d = 32; d; d >>= 1) {
    a0 += __shfl_xor(a0, d); a1 += __shfl_xor(a1, d); a2 += __shfl_xor(a2, d);
    a3 += __shfl_xor(a3, d); a4 += __shfl_xor(a4, d);
  }
  if (lane == 0) {
    float sc = isd * isd;
    const float* xi = x + (size_t)wid * 5;
    float* o = xagg + (size_t)wid * 5;
    o[0] = a0 + xi[0] * sc; o[1] = a1 + xi[1] * sc; o[2] = a2 + xi[2] * sc;
    o[3] = a3 + xi[3] * sc; o[4] = a4 + xi[4] * sc;
  }
}

// h1 = relu(xagg @ W1 + b1)   (wave per node, lane = output feature)
__global__ void k_l1(const float* __restrict__ xagg, const float* __restrict__ W1,
                     const float* __restrict__ b1, float* __restrict__ h, int n) {
  __shared__ float w[320];
  __shared__ float bsh[64];
  int tid = threadIdx.x;
  for (int i = tid; i < 320; i += 256) w[i] = W1[i];
  if (tid < 64) bsh[tid] = b1[tid];
  __syncthreads();
  int wid = (blockIdx.x * blockDim.x + tid) >> 6;
  int lane = tid & 63;
  if (wid >= n) return;
  const float* xi = xagg + (size_t)wid * 5;
  float acc = bsh[lane];
#pragma unroll
  for (int k = 0; k < 5; ++k) acc = fmaf(xi[k], w[k * 64 + lane], acc);
  h[(size_t)wid * 64 + lane] = fmaxf(acc, 0.f);
}

// h2raw = h1 @ W2  (wave-strided over nodes; W2 column in registers; shfl-broadcast row)
__global__ void k_hw2(const float* __restrict__ hin, const float* __restrict__ W2,
                      float* __restrict__ hout, int n) {
  int lane = threadIdx.x & 63;
  float wreg[64];
#pragma unroll
  for (int k = 0; k < 64; ++k) wreg[k] = W2[k * 64 + lane];
  int wid = (blockIdx.x * blockDim.x + threadIdx.x) >> 6;
  int nw = (gridDim.x * blockDim.x) >> 6;
  for (int i = wid; i < n; i += nw) {
    float hv = hin[(size_t)i * 64 + lane];
    float acc0 = 0.f, acc1 = 0.f, acc2 = 0.f, acc3 = 0.f;
#pragma unroll
    for (int k = 0; k < 64; k += 4) {
      acc0 = fmaf(__shfl(hv, k),     wreg[k],     acc0);
      acc1 = fmaf(__shfl(hv, k + 1), wreg[k + 1], acc1);
      acc2 = fmaf(__shfl(hv, k + 2), wreg[k + 2], acc2);
      acc3 = fmaf(__shfl(hv, k + 3), wreg[k + 3], acc3);
    }
    hout[(size_t)i * 64 + lane] = (acc0 + acc1) + (acc2 + acc3);
  }
}

// 64-dim aggregation: hout = relu(A_norm @ hraw + b)
// 4 edges in flight per wave: lane = (sub 0..3, fl 0..15); each thread float4.
template <bool RELU>
__global__ void k_agg64(const float* __restrict__ hraw, const int* __restrict__ offs,
                        const int* __restrict__ srcs, const float* __restrict__ inv_sqrt,
                        const float* __restrict__ bias, float* __restrict__ hout, int n) {
  int wid = (blockIdx.x * blockDim.x + threadIdx.x) >> 6;
  int lane = threadIdx.x & 63;
  if (wid >= n) return;
  int sub = lane >> 4;     // edge slot 0..3
  int fl  = lane & 15;     // feature quad 0..15
  int beg = offs[wid], end = offs[wid + 1];
  float isd = inv_sqrt[wid];
  float ax = 0.f, ay = 0.f, az = 0.f, aw = 0.f;
  for (int j = beg + sub; j < end; j += 4) {
    int s = srcs[j];                       // same addr across 16-lane group -> broadcast
    float c = inv_sqrt[s] * isd;
    float4 r = *(const float4*)(hraw + (size_t)s * 64 + fl * 4);
    ax = fmaf(r.x, c, ax); ay = fmaf(r.y, c, ay);
    az = fmaf(r.z, c, az); aw = fmaf(r.w, c, aw);
  }
  // reduce the 4 edge slots (lanes fl, fl+16, fl+32, fl+48)
  ax += __shfl_xor(ax, 16); ay += __shfl_xor(ay, 16);
  az += __shfl_xor(az, 16); aw += __shfl_xor(aw, 16);
  ax += __shfl_xor(ax, 32); ay += __shfl_xor(ay, 32);
  az += __shfl_xor(az, 32); aw += __shfl_xor(aw, 32);
  if (sub == 0) {
    float sc = isd * isd;
    float4 self = *(const float4*)(hraw + (size_t)wid * 64 + fl * 4);
    float4 bb   = *(const float4*)(bias + fl * 4);
    float4 o;
    o.x = ax + self.x * sc + bb.x;
    o.y = ay + self.y * sc + bb.y;
    o.z = az + self.z * sc + bb.z;
    o.w = aw + self.w * sc + bb.w;
    if (RELU) {
      o.x = fmaxf(o.x, 0.f); o.y = fmaxf(o.y, 0.f);
      o.z = fmaxf(o.z, 0.f); o.w = fmaxf(o.w, 0.f);
    }
    *(float4*)(hout + (size_t)wid * 64 + fl * 4) = o;
  }
}

// h3 = h2 @ W3  (64 -> 2; wave per node, lane = k, shfl reduce)
__global__ void k_hw3(const float* __restrict__ hin, const float* __restrict__ W3,
                      float* __restrict__ h3, int n) {
  int lane = threadIdx.x & 63;
  float w0 = W3[lane * 2], w1 = W3[lane * 2 + 1];
  int wid = (blockIdx.x * blockDim.x + threadIdx.x) >> 6;
  int nw = (gridDim.x * blockDim.x) >> 6;
  for (int i = wid; i < n; i += nw) {
    float hv = hin[(size_t)i * 64 + lane];
    float a0 = hv * w0, a1 = hv * w1;
#pragma unroll
    for (int d = 32; d; d >>= 1) { a0 += __shfl_xor(a0, d); a1 += __shfl_xor(a1, d); }
    if (lane == 0) { h3[(size_t)i * 2] = a0; h3[(size_t)i * 2 + 1] = a1; }
  }
}

// out = A_norm @ h3 + self + b3  (wave per node, lanes cooperate over edges)
__global__ void k_agg2(const float* __restrict__ h3, const int* __restrict__ offs,
                       const int* __restrict__ srcs, const float* __restrict__ inv_sqrt,
                       const float* __restrict__ b3, float* __restrict__ out, int n) {
  int wid = (blockIdx.x * blockDim.x + threadIdx.x) >> 6;
  int lane = threadIdx.x & 63;
  if (wid >= n) return;
  int beg = offs[wid], end = offs[wid + 1];
  float isd = inv_sqrt[wid];
  float a0 = 0.f, a1 = 0.f;
  for (int j = beg + lane; j < end; j += 64) {
    int s = srcs[j];
    float c = inv_sqrt[s] * isd;
    a0 = fmaf(h3[(size_t)s * 2], c, a0);
    a1 = fmaf(h3[(size_t)s * 2 + 1], c, a1);
  }
#pragma unroll
  for (int d = 32; d; d >>= 1) { a0 += __shfl_xor(a0, d); a1 += __shfl_xor(a1, d); }
  if (lane == 0) {
    float sc = isd * isd;
    out[(size_t)wid * 2]     = a0 + h3[(size_t)wid * 2] * sc + b3[0];
    out[(size_t)wid * 2 + 1] = a1 + h3[(size_t)wid * 2 + 1] * sc + b3[1];
  }
}

// ---------------- launcher ----------------

extern "C" void kernel_launch(void* const* d_in, const int* in_sizes, int n_in,
                              void* d_out, int out_size, void* d_ws, size_t ws_size,
                              hipStream_t stream) {
  const float* x  = (const float*)d_in[0];
  const int*   ei = (const int*)d_in[1];
  const float* W1 = (const float*)d_in[2];
  const float* b1 = (const float*)d_in[3];
  const float* W2 = (const float*)d_in[4];
  const float* b2 = (const float*)d_in[5];
  const float* W3 = (const float*)d_in[6];
  const float* b3 = (const float*)d_in[7];
  float* out = (float*)d_out;

  const int N = in_sizes[0] / 5;
  const int E = in_sizes[1] / 2;
  const int* src = ei;
  const int* dst = ei + E;

  char* p = (char*)d_ws;
  auto alloc = [&](size_t bytes) {
    char* r = p;
    p += (bytes + 255) & ~(size_t)255;
    return r;
  };
  const int nb = (N + 1023) / 1024;
  float* inv_sqrt  = (float*)alloc((size_t)N * 4);
  int*   cnt       = (int*)alloc((size_t)N * 4);
  int*   offs      = (int*)alloc((size_t)(N + 1) * 4);
  int*   nxt       = (int*)alloc((size_t)N * 4);
  int*   blockSums = (int*)alloc((size_t)nb * 4);
  int*   blockOffs = (int*)alloc((size_t)(nb + 1) * 4);
  int*   srcs      = (int*)alloc((size_t)E * 4);
  float* xagg      = (float*)alloc((size_t)N * 5 * 4);
  float* h3        = (float*)alloc((size_t)N * 2 * 4);
  float* hA        = (float*)alloc((size_t)N * 64 * 4);
  float* hB        = (float*)alloc((size_t)N * 64 * 4);

  const int wavesBlocks = (N * 64 + 255) / 256;  // one wave per node

  k_zero<<<512, 256, 0, stream>>>(cnt, N);
  k_count<<<2048, 256, 0, stream>>>(dst, cnt, E);
  k_scan_local<<<nb, 1024, 0, stream>>>(cnt, offs, blockSums, N);
  k_scan_blocks<<<1, 64, 0, stream>>>(blockSums, blockOffs, nb);
  k_scan_add<<<nb, 1024, 0, stream>>>(offs, blockOffs, cnt, inv_sqrt, nxt, N);
  k_fill<<<2048, 256, 0, stream>>>(src, dst, nxt, srcs, E);

  // layer 1: aggregate 5-dim x, then project+bias+relu
  k_agg5<<<wavesBlocks, 256, 0, stream>>>(x, offs, srcs, inv_sqrt, xagg, N);
  k_l1<<<wavesBlocks, 256, 0, stream>>>(xagg, W1, b1, hA, N);

  // layer 2: project 64->64, aggregate 64-dim with bias+relu
  k_hw2<<<2048, 256, 0, stream>>>(hA, W2, hB, N);
  k_agg64<true><<<wavesBlocks, 256, 0, stream>>>(hB, offs, srcs, inv_sqrt, b2, hA, N);

  // layer 3: project 64->2, aggregate 2-dim with bias
  k_hw3<<<2048, 256, 0, stream>>>(hA, W3, h3, N);
  k_agg2<<<wavesBlocks, 256, 0, stream>>>(h3, offs, srcs, inv_sqrt, b3, out, N);
}

// Round 4
// 375.530 us; speedup vs baseline: 2.2107x; 1.9291x over previous
//
#include <hip/hip_runtime.h>

#define CB 512        // chunk-blocks for hist/scatter
#define MAXNB 1024    // max buckets (N <= 262144)

// ---------------- bucket-sort CSR build (no global atomics) ----------------

// per-block bucket histogram, bucket = dst >> 8 (256 nodes per bucket)
__global__ void k_hist(const int* __restrict__ dst, int* __restrict__ histG,
                       int E, int NB, int chunk) {
  __shared__ int hist[MAXNB];
  int b = blockIdx.x, tid = threadIdx.x;
  for (int k = tid; k < NB; k += 256) hist[k] = 0;
  __syncthreads();
  int beg = b * chunk, end = min(E, beg + chunk);
  for (int i = beg + tid; i < end; i += 256) atomicAdd(&hist[dst[i] >> 8], 1);
  __syncthreads();
  for (int k = tid; k < NB; k += 256) histG[(size_t)k * CB + b] = hist[k];
}

// generic exclusive scan: per-block (1024) local scan + block totals
__global__ void k_scan_local(const int* __restrict__ in, int* __restrict__ out,
                             int* __restrict__ blockSums, int n) {
  __shared__ int wsum[16];
  __shared__ int wpre[16];
  int tid = threadIdx.x;
  int gid = blockIdx.x * 1024 + tid;
  int v = (gid < n) ? in[gid] : 0;
  int lane = tid & 63, wv = tid >> 6;
  int x = v;
#pragma unroll
  for (int d = 1; d < 64; d <<= 1) {
    int t = __shfl_up(x, d);
    if (lane >= d) x += t;
  }
  if (lane == 63) wsum[wv] = x;
  __syncthreads();
  if (tid == 0) {
    int run = 0;
#pragma unroll
    for (int i = 0; i < 16; ++i) { wpre[i] = run; run += wsum[i]; }
    blockSums[blockIdx.x] = run;
  }
  __syncthreads();
  if (gid < n) out[gid] = x - v + wpre[wv];
}

__global__ void k_scan_blocks(const int* __restrict__ blockSums, int* __restrict__ blockOffs, int nb) {
  if (threadIdx.x == 0 && blockIdx.x == 0) {
    int run = 0;
    for (int i = 0; i < nb; ++i) { blockOffs[i] = run; run += blockSums[i]; }
    blockOffs[nb] = run;
  }
}

__global__ void k_scan_addg(int* __restrict__ data, const int* __restrict__ blockOffs, int n) {
  int gid = blockIdx.x * 1024 + threadIdx.x;
  if (gid < n) data[gid] += blockOffs[blockIdx.x];
}

// stable scatter into bucketed record array; rec = (src<<8) | (dst&255)
__global__ void k_scatter(const int* __restrict__ src, const int* __restrict__ dst,
                          const int* __restrict__ histS, unsigned* __restrict__ recs,
                          int E, int NB, int chunk) {
  __shared__ int cur[MAXNB];
  int b = blockIdx.x, tid = threadIdx.x;
  for (int k = tid; k < NB; k += 256) cur[k] = histS[(size_t)k * CB + b];
  __syncthreads();
  int beg = b * chunk, end = min(E, beg + chunk);
  for (int i = beg + tid; i < end; i += 256) {
    int s = src[i], d = dst[i];
    int pos = atomicAdd(&cur[d >> 8], 1);
    recs[pos] = ((unsigned)s << 8) | (unsigned)(d & 255);
  }
}

// per-bucket: degree count + local scan -> offs/inv_sqrt, then counting-sort srcs
__global__ void k_build(const unsigned* __restrict__ recs, const int* __restrict__ histS,
                        int* __restrict__ offs, float* __restrict__ inv_sqrt,
                        int* __restrict__ srcs, int N, int NB, int E) {
  __shared__ int cnt[256];
  __shared__ int cur[256];
  __shared__ int wtot[4];
  int k = blockIdx.x, tid = threadIdx.x;
  int ebeg = histS[(size_t)k * CB];
  int eend = (k + 1 < NB) ? histS[(size_t)(k + 1) * CB] : E;
  cnt[tid] = 0;
  __syncthreads();
  for (int i = ebeg + tid; i < eend; i += 256) atomicAdd(&cnt[recs[i] & 255u], 1);
  __syncthreads();
  int v = cnt[tid];
  int lane = tid & 63, w = tid >> 6;
  int x = v;
#pragma unroll
  for (int d = 1; d < 64; d <<= 1) {
    int t = __shfl_up(x, d);
    if (lane >= d) x += t;
  }
  if (lane == 63) wtot[w] = x;
  __syncthreads();
  int pre = 0;
  for (int i = 0; i < w; ++i) pre += wtot[i];
  int gpos = ebeg + (x - v) + pre;
  int node = k * 256 + tid;
  if (node < N) {
    offs[node] = gpos;
    inv_sqrt[node] = rsqrtf(1.0f + (float)v);
  }
  cur[tid] = gpos;
  if (k == NB - 1 && tid == 0) offs[N] = E;
  __syncthreads();
  for (int i = ebeg + tid; i < eend; i += 256) {
    unsigned r = recs[i];
    int pos = atomicAdd(&cur[r & 255u], 1);
    srcs[pos] = (int)(r >> 8);
  }
}

// ---------------- layer kernels (unchanged from passing round) ----------------

__global__ void k_agg5(const float* __restrict__ x, const int* __restrict__ offs,
                       const int* __restrict__ srcs, const float* __restrict__ inv_sqrt,
                       float* __restrict__ xagg, int n) {
  int wid = (blockIdx.x * blockDim.x + threadIdx.x) >> 6;
  int lane = threadIdx.x & 63;
  if (wid >= n) return;
  int beg = offs[wid], end = offs[wid + 1];
  float isd = inv_sqrt[wid];
  float a0 = 0.f, a1 = 0.f, a2 = 0.f, a3 = 0.f, a4 = 0.f;
  for (int j = beg + lane; j < end; j += 64) {
    int s = srcs[j];
    float c = inv_sqrt[s] * isd;
    const float* xs = x + (size_t)s * 5;
    a0 = fmaf(xs[0], c, a0); a1 = fmaf(xs[1], c, a1); a2 = fmaf(xs[2], c, a2);
    a3 = fmaf(xs[3], c, a3); a4 = fmaf(xs[4], c, a4);
  }
#pragma unroll
  for (int d = 32; d; d >>= 1) {
    a0 += __shfl_xor(a0, d); a1 += __shfl_xor(a1, d); a2 += __shfl_xor(a2, d);
    a3 += __shfl_xor(a3, d); a4 += __shfl_xor(a4, d);
  }
  if (lane == 0) {
    float sc = isd * isd;
    const float* xi = x + (size_t)wid * 5;
    float* o = xagg + (size_t)wid * 5;
    o[0] = a0 + xi[0] * sc; o[1] = a1 + xi[1] * sc; o[2] = a2 + xi[2] * sc;
    o[3] = a3 + xi[3] * sc; o[4] = a4 + xi[4] * sc;
  }
}

__global__ void k_l1(const float* __restrict__ xagg, const float* __restrict__ W1,
                     const float* __restrict__ b1, float* __restrict__ h, int n) {
  __shared__ float w[320];
  __shared__ float bsh[64];
  int tid = threadIdx.x;
  for (int i = tid; i < 320; i += 256) w[i] = W1[i];
  if (tid < 64) bsh[tid] = b1[tid];
  __syncthreads();
  int wid = (blockIdx.x * blockDim.x + tid) >> 6;
  int lane = tid & 63;
  if (wid >= n) return;
  const float* xi = xagg + (size_t)wid * 5;
  float acc = bsh[lane];
#pragma unroll
  for (int k = 0; k < 5; ++k) acc = fmaf(xi[k], w[k * 64 + lane], acc);
  h[(size_t)wid * 64 + lane] = fmaxf(acc, 0.f);
}

__global__ void k_hw2(const float* __restrict__ hin, const float* __restrict__ W2,
                      float* __restrict__ hout, int n) {
  int lane = threadIdx.x & 63;
  float wreg[64];
#pragma unroll
  for (int k = 0; k < 64; ++k) wreg[k] = W2[k * 64 + lane];
  int wid = (blockIdx.x * blockDim.x + threadIdx.x) >> 6;
  int nw = (gridDim.x * blockDim.x) >> 6;
  for (int i = wid; i < n; i += nw) {
    float hv = hin[(size_t)i * 64 + lane];
    float acc0 = 0.f, acc1 = 0.f, acc2 = 0.f, acc3 = 0.f;
#pragma unroll
    for (int k = 0; k < 64; k += 4) {
      acc0 = fmaf(__shfl(hv, k),     wreg[k],     acc0);
      acc1 = fmaf(__shfl(hv, k + 1), wreg[k + 1], acc1);
      acc2 = fmaf(__shfl(hv, k + 2), wreg[k + 2], acc2);
      acc3 = fmaf(__shfl(hv, k + 3), wreg[k + 3], acc3);
    }
    hout[(size_t)i * 64 + lane] = (acc0 + acc1) + (acc2 + acc3);
  }
}

template <bool RELU>
__global__ void k_agg64(const float* __restrict__ hraw, const int* __restrict__ offs,
                        const int* __restrict__ srcs, const float* __restrict__ inv_sqrt,
                        const float* __restrict__ bias, float* __restrict__ hout, int n) {
  int wid = (blockIdx.x * blockDim.x + threadIdx.x) >> 6;
  int lane = threadIdx.x & 63;
  if (wid >= n) return;
  int sub = lane >> 4;
  int fl  = lane & 15;
  int beg = offs[wid], end = offs[wid + 1];
  float isd = inv_sqrt[wid];
  float ax = 0.f, ay = 0.f, az = 0.f, aw = 0.f;
  for (int j = beg + sub; j < end; j += 4) {
    int s = srcs[j];
    float c = inv_sqrt[s] * isd;
    float4 r = *(const float4*)(hraw + (size_t)s * 64 + fl * 4);
    ax = fmaf(r.x, c, ax); ay = fmaf(r.y, c, ay);
    az = fmaf(r.z, c, az); aw = fmaf(r.w, c, aw);
  }
  ax += __shfl_xor(ax, 16); ay += __shfl_xor(ay, 16);
  az += __shfl_xor(az, 16); aw += __shfl_xor(aw, 16);
  ax += __shfl_xor(ax, 32); ay += __shfl_xor(ay, 32);
  az += __shfl_xor(az, 32); aw += __shfl_xor(aw, 32);
  if (sub == 0) {
    float sc = isd * isd;
    float4 self = *(const float4*)(hraw + (size_t)wid * 64 + fl * 4);
    float4 bb   = *(const float4*)(bias + fl * 4);
    float4 o;
    o.x = ax + self.x * sc + bb.x;
    o.y = ay + self.y * sc + bb.y;
    o.z = az + self.z * sc + bb.z;
    o.w = aw + self.w * sc + bb.w;
    if (RELU) {
      o.x = fmaxf(o.x, 0.f); o.y = fmaxf(o.y, 0.f);
      o.z = fmaxf(o.z, 0.f); o.w = fmaxf(o.w, 0.f);
    }
    *(float4*)(hout + (size_t)wid * 64 + fl * 4) = o;
  }
}

__global__ void k_hw3(const float* __restrict__ hin, const float* __restrict__ W3,
                      float* __restrict__ h3, int n) {
  int lane = threadIdx.x & 63;
  float w0 = W3[lane * 2], w1 = W3[lane * 2 + 1];
  int wid = (blockIdx.x * blockDim.x + threadIdx.x) >> 6;
  int nw = (gridDim.x * blockDim.x) >> 6;
  for (int i = wid; i < n; i += nw) {
    float hv = hin[(size_t)i * 64 + lane];
    float a0 = hv * w0, a1 = hv * w1;
#pragma unroll
    for (int d = 32; d; d >>= 1) { a0 += __shfl_xor(a0, d); a1 += __shfl_xor(a1, d); }
    if (lane == 0) { h3[(size_t)i * 2] = a0; h3[(size_t)i * 2 + 1] = a1; }
  }
}

__global__ void k_agg2(const float* __restrict__ h3, const int* __restrict__ offs,
                       const int* __restrict__ srcs, const float* __restrict__ inv_sqrt,
                       const float* __restrict__ b3, float* __restrict__ out, int n) {
  int wid = (blockIdx.x * blockDim.x + threadIdx.x) >> 6;
  int lane = threadIdx.x & 63;
  if (wid >= n) return;
  int beg = offs[wid], end = offs[wid + 1];
  float isd = inv_sqrt[wid];
  float a0 = 0.f, a1 = 0.f;
  for (int j = beg + lane; j < end; j += 64) {
    int s = srcs[j];
    float c = inv_sqrt[s] * isd;
    a0 = fmaf(h3[(size_t)s * 2], c, a0);
    a1 = fmaf(h3[(size_t)s * 2 + 1], c, a1);
  }
#pragma unroll
  for (int d = 32; d; d >>= 1) { a0 += __shfl_xor(a0, d); a1 += __shfl_xor(a1, d); }
  if (lane == 0) {
    float sc = isd * isd;
    out[(size_t)wid * 2]     = a0 + h3[(size_t)wid * 2] * sc + b3[0];
    out[(size_t)wid * 2 + 1] = a1 + h3[(size_t)wid * 2 + 1] * sc + b3[1];
  }
}

// ---------------- launcher ----------------

extern "C" void kernel_launch(void* const* d_in, const int* in_sizes, int n_in,
                              void* d_out, int out_size, void* d_ws, size_t ws_size,
                              hipStream_t stream) {
  const float* x  = (const float*)d_in[0];
  const int*   ei = (const int*)d_in[1];
  const float* W1 = (const float*)d_in[2];
  const float* b1 = (const float*)d_in[3];
  const float* W2 = (const float*)d_in[4];
  const float* b2 = (const float*)d_in[5];
  const float* W3 = (const float*)d_in[6];
  const float* b3 = (const float*)d_in[7];
  float* out = (float*)d_out;

  const int N = in_sizes[0] / 5;
  const int E = in_sizes[1] / 2;
  const int* src = ei;
  const int* dst = ei + E;

  const int NB = (N + 255) >> 8;          // buckets of 256 nodes
  const int chunk = (E + CB - 1) / CB;    // edges per hist/scatter block
  const int n2 = NB * CB;                 // histogram entries
  const int nb2 = (n2 + 1023) / 1024;     // scan blocks

  char* p = (char*)d_ws;
  auto alloc = [&](size_t bytes) {
    char* r = p;
    p += (bytes + 255) & ~(size_t)255;
    return r;
  };
  int*      histG     = (int*)alloc((size_t)n2 * 4);
  int*      histS     = (int*)alloc((size_t)n2 * 4);
  int*      blockSums = (int*)alloc((size_t)nb2 * 4);
  int*      blockOffs = (int*)alloc((size_t)(nb2 + 1) * 4);
  unsigned* recs      = (unsigned*)alloc((size_t)E * 4);
  int*      srcs      = (int*)alloc((size_t)E * 4);
  int*      offs      = (int*)alloc((size_t)(N + 1) * 4);
  float*    inv_sqrt  = (float*)alloc((size_t)N * 4);
  float*    xagg      = (float*)alloc((size_t)N * 5 * 4);
  float*    h3        = (float*)alloc((size_t)N * 2 * 4);
  float*    hA        = (float*)alloc((size_t)N * 64 * 4);
  float*    hB        = (float*)alloc((size_t)N * 64 * 4);

  const int wavesBlocks = (N * 64 + 255) / 256;  // one wave per node

  // CSR build via stable bucket sort — zero global atomics
  k_hist<<<CB, 256, 0, stream>>>(dst, histG, E, NB, chunk);
  k_scan_local<<<nb2, 1024, 0, stream>>>(histG, histS, blockSums, n2);
  k_scan_blocks<<<1, 64, 0, stream>>>(blockSums, blockOffs, nb2);
  k_scan_addg<<<nb2, 1024, 0, stream>>>(histS, blockOffs, n2);
  k_scatter<<<CB, 256, 0, stream>>>(src, dst, histS, recs, E, NB, chunk);
  k_build<<<NB, 256, 0, stream>>>(recs, histS, offs, inv_sqrt, srcs, N, NB, E);

  // layer 1: aggregate 5-dim x, then project+bias+relu
  k_agg5<<<wavesBlocks, 256, 0, stream>>>(x, offs, srcs, inv_sqrt, xagg, N);
  k_l1<<<wavesBlocks, 256, 0, stream>>>(xagg, W1, b1, hA, N);

  // layer 2: project 64->64, aggregate 64-dim with bias+relu
  k_hw2<<<2048, 256, 0, stream>>>(hA, W2, hB, N);
  k_agg64<true><<<wavesBlocks, 256, 0, stream>>>(hB, offs, srcs, inv_sqrt, b2, hA, N);

  // layer 3: project 64->2, aggregate 2-dim with bias
  k_hw3<<<2048, 256, 0, stream>>>(hA, W3, h3, N);
  k_agg2<<<wavesBlocks, 256, 0, stream>>>(h3, offs, srcs, inv_sqrt, b3, out, N);
}

// Round 5
// 293.185 us; speedup vs baseline: 2.8316x; 1.2809x over previous
//
#include <hip/hip_runtime.h>

#define CB 256        // chunk-blocks for hist/scatter
#define MAXNB 1024    // max buckets (N <= 262144)

// ---------------- bucket-sort CSR build (no global atomics) ----------------

__global__ void k_hist(const int* __restrict__ dst, int* __restrict__ histG,
                       int E, int NB, int chunk) {
  __shared__ int hist[MAXNB];
  int b = blockIdx.x, tid = threadIdx.x;
  for (int k = tid; k < NB; k += 256) hist[k] = 0;
  __syncthreads();
  int beg = b * chunk, end = min(E, beg + chunk);
  for (int i = beg + tid; i < end; i += 256) atomicAdd(&hist[dst[i] >> 8], 1);
  __syncthreads();
  for (int k = tid; k < NB; k += 256) histG[(size_t)k * CB + b] = hist[k];
}

__global__ void k_scan_local(const int* __restrict__ in, int* __restrict__ out,
                             int* __restrict__ blockSums, int n) {
  __shared__ int wsum[16];
  __shared__ int wpre[16];
  int tid = threadIdx.x;
  int gid = blockIdx.x * 1024 + tid;
  int v = (gid < n) ? in[gid] : 0;
  int lane = tid & 63, wv = tid >> 6;
  int x = v;
#pragma unroll
  for (int d = 1; d < 64; d <<= 1) {
    int t = __shfl_up(x, d);
    if (lane >= d) x += t;
  }
  if (lane == 63) wsum[wv] = x;
  __syncthreads();
  if (tid == 0) {
    int run = 0;
#pragma unroll
    for (int i = 0; i < 16; ++i) { wpre[i] = run; run += wsum[i]; }
    blockSums[blockIdx.x] = run;
  }
  __syncthreads();
  if (gid < n) out[gid] = x - v + wpre[wv];
}

__global__ void k_scan_blocks(const int* __restrict__ blockSums, int* __restrict__ blockOffs, int nb) {
  if (threadIdx.x == 0 && blockIdx.x == 0) {
    int run = 0;
    for (int i = 0; i < nb; ++i) { blockOffs[i] = run; run += blockSums[i]; }
    blockOffs[nb] = run;
  }
}

__global__ void k_scan_addg(int* __restrict__ data, const int* __restrict__ blockOffs, int n) {
  int gid = blockIdx.x * 1024 + threadIdx.x;
  if (gid < n) data[gid] += blockOffs[blockIdx.x];
}

__global__ void k_scatter(const int* __restrict__ src, const int* __restrict__ dst,
                          const int* __restrict__ histS, unsigned* __restrict__ recs,
                          int E, int NB, int chunk) {
  __shared__ int cur[MAXNB];
  int b = blockIdx.x, tid = threadIdx.x;
  for (int k = tid; k < NB; k += 256) cur[k] = histS[(size_t)k * CB + b];
  __syncthreads();
  int beg = b * chunk, end = min(E, beg + chunk);
  for (int i = beg + tid; i < end; i += 256) {
    int s = src[i], d = dst[i];
    int pos = atomicAdd(&cur[d >> 8], 1);
    recs[pos] = ((unsigned)s << 8) | (unsigned)(d & 255);
  }
}

__global__ void k_build(const unsigned* __restrict__ recs, const int* __restrict__ histS,
                        int* __restrict__ offs, float* __restrict__ inv_sqrt,
                        int* __restrict__ srcs, int N, int NB, int E) {
  __shared__ int cnt[256];
  __shared__ int cur[256];
  __shared__ int wtot[4];
  int k = blockIdx.x, tid = threadIdx.x;
  int ebeg = histS[(size_t)k * CB];
  int eend = (k + 1 < NB) ? histS[(size_t)(k + 1) * CB] : E;
  cnt[tid] = 0;
  __syncthreads();
  for (int i = ebeg + tid; i < eend; i += 256) atomicAdd(&cnt[recs[i] & 255u], 1);
  __syncthreads();
  int v = cnt[tid];
  int lane = tid & 63, w = tid >> 6;
  int x = v;
#pragma unroll
  for (int d = 1; d < 64; d <<= 1) {
    int t = __shfl_up(x, d);
    if (lane >= d) x += t;
  }
  if (lane == 63) wtot[w] = x;
  __syncthreads();
  int pre = 0;
  for (int i = 0; i < w; ++i) pre += wtot[i];
  int gpos = ebeg + (x - v) + pre;
  int node = k * 256 + tid;
  if (node < N) {
    offs[node] = gpos;
    inv_sqrt[node] = rsqrtf(1.0f + (float)v);
  }
  cur[tid] = gpos;
  if (k == NB - 1 && tid == 0) offs[N] = E;
  __syncthreads();
  for (int i = ebeg + tid; i < eend; i += 256) {
    unsigned r = recs[i];
    int pos = atomicAdd(&cur[r & 255u], 1);
    srcs[pos] = (int)(r >> 8);
  }
}

// ---------------- layer kernels ----------------

// layer 1 fused: xagg = A_norm @ x, then h1 = relu(xagg @ W1 + b1)
__global__ void k_agg5l1(const float* __restrict__ x, const int* __restrict__ offs,
                         const int* __restrict__ srcs, const float* __restrict__ inv_sqrt,
                         const float* __restrict__ W1, const float* __restrict__ b1,
                         float* __restrict__ h1, int n) {
  int wid = (blockIdx.x * blockDim.x + threadIdx.x) >> 6;
  int lane = threadIdx.x & 63;
  if (wid >= n) return;
  float w1r[5];
#pragma unroll
  for (int k = 0; k < 5; ++k) w1r[k] = W1[k * 64 + lane];
  float bias = b1[lane];
  int beg = offs[wid], end = offs[wid + 1];
  float isd = inv_sqrt[wid];
  float a0 = 0.f, a1 = 0.f, a2 = 0.f, a3 = 0.f, a4 = 0.f;
  for (int j = beg + lane; j < end; j += 64) {
    int s = srcs[j];
    float c = inv_sqrt[s] * isd;
    const float* xs = x + (size_t)s * 5;
    a0 = fmaf(xs[0], c, a0); a1 = fmaf(xs[1], c, a1); a2 = fmaf(xs[2], c, a2);
    a3 = fmaf(xs[3], c, a3); a4 = fmaf(xs[4], c, a4);
  }
#pragma unroll
  for (int d = 32; d; d >>= 1) {
    a0 += __shfl_xor(a0, d); a1 += __shfl_xor(a1, d); a2 += __shfl_xor(a2, d);
    a3 += __shfl_xor(a3, d); a4 += __shfl_xor(a4, d);
  }
  // all 64 lanes now hold the full aggregation sums; add self term (uniform loads)
  float sc = isd * isd;
  const float* xi = x + (size_t)wid * 5;
  a0 = fmaf(xi[0], sc, a0); a1 = fmaf(xi[1], sc, a1); a2 = fmaf(xi[2], sc, a2);
  a3 = fmaf(xi[3], sc, a3); a4 = fmaf(xi[4], sc, a4);
  float acc = bias;
  acc = fmaf(a0, w1r[0], acc); acc = fmaf(a1, w1r[1], acc); acc = fmaf(a2, w1r[2], acc);
  acc = fmaf(a3, w1r[3], acc); acc = fmaf(a4, w1r[4], acc);
  h1[(size_t)wid * 64 + lane] = fmaxf(acc, 0.f);
}

// h2raw = h1 @ W2 : wave-private LDS row staging + broadcast ds_read_b128
__global__ void k_hw2(const float* __restrict__ hin, const float* __restrict__ W2,
                      float* __restrict__ hout, int n) {
  __shared__ float hrow[4 * 64];
  int tid = threadIdx.x;
  int lane = tid & 63, w = tid >> 6;
  float wreg[64];
#pragma unroll
  for (int k = 0; k < 64; ++k) wreg[k] = W2[k * 64 + lane];
  float* slot = &hrow[w * 64];
  int wid = (blockIdx.x * blockDim.x + tid) >> 6;
  int nw = (gridDim.x * blockDim.x) >> 6;
  for (int i = wid; i < n; i += nw) {
    slot[lane] = hin[(size_t)i * 64 + lane];   // wave-private slot; DS pipe is in-order per wave
    float acc0 = 0.f, acc1 = 0.f, acc2 = 0.f, acc3 = 0.f;
#pragma unroll
    for (int k4 = 0; k4 < 16; ++k4) {
      float4 hq = *(const float4*)&slot[k4 * 4];  // same addr all lanes -> broadcast
      acc0 = fmaf(hq.x, wreg[k4 * 4],     acc0);
      acc1 = fmaf(hq.y, wreg[k4 * 4 + 1], acc1);
      acc2 = fmaf(hq.z, wreg[k4 * 4 + 2], acc2);
      acc3 = fmaf(hq.w, wreg[k4 * 4 + 3], acc3);
    }
    hout[(size_t)i * 64 + lane] = (acc0 + acc1) + (acc2 + acc3);
  }
}

// layers 2+3 fused: h2 = relu(A_norm @ h2raw + b2); h3 = h2 @ W3  (never materialize h2)
__global__ void k_agg64w3(const float* __restrict__ hraw, const int* __restrict__ offs,
                          const int* __restrict__ srcs, const float* __restrict__ inv_sqrt,
                          const float* __restrict__ b2, const float* __restrict__ W3,
                          float* __restrict__ h3, int n) {
  int wid = (blockIdx.x * blockDim.x + threadIdx.x) >> 6;
  int lane = threadIdx.x & 63;
  if (wid >= n) return;
  int sub = lane >> 4;
  int fl  = lane & 15;
  // W3 fragment for this lane's 4 features
  float w30[4], w31[4];
#pragma unroll
  for (int q = 0; q < 4; ++q) {
    w30[q] = W3[(fl * 4 + q) * 2];
    w31[q] = W3[(fl * 4 + q) * 2 + 1];
  }
  int beg = offs[wid], end = offs[wid + 1];
  float isd = inv_sqrt[wid];
  float ax0 = 0.f, ay0 = 0.f, az0 = 0.f, aw0 = 0.f;
  float ax1 = 0.f, ay1 = 0.f, az1 = 0.f, aw1 = 0.f;
  int j = beg + sub;
  // 2x unrolled: 8 independent row-gathers in flight per wave
  for (; j + 4 < end; j += 8) {
    int s0 = srcs[j], s1 = srcs[j + 4];
    float c0 = inv_sqrt[s0] * isd, c1 = inv_sqrt[s1] * isd;
    float4 r0 = *(const float4*)(hraw + (size_t)s0 * 64 + fl * 4);
    float4 r1 = *(const float4*)(hraw + (size_t)s1 * 64 + fl * 4);
    ax0 = fmaf(r0.x, c0, ax0); ay0 = fmaf(r0.y, c0, ay0);
    az0 = fmaf(r0.z, c0, az0); aw0 = fmaf(r0.w, c0, aw0);
    ax1 = fmaf(r1.x, c1, ax1); ay1 = fmaf(r1.y, c1, ay1);
    az1 = fmaf(r1.z, c1, az1); aw1 = fmaf(r1.w, c1, aw1);
  }
  if (j < end) {
    int s0 = srcs[j];
    float c0 = inv_sqrt[s0] * isd;
    float4 r0 = *(const float4*)(hraw + (size_t)s0 * 64 + fl * 4);
    ax0 = fmaf(r0.x, c0, ax0); ay0 = fmaf(r0.y, c0, ay0);
    az0 = fmaf(r0.z, c0, az0); aw0 = fmaf(r0.w, c0, aw0);
  }
  float ax = ax0 + ax1, ay = ay0 + ay1, az = az0 + az1, aw = aw0 + aw1;
  // reduce over the 4 edge slots -> all lanes hold full sums for their fl chunk
  ax += __shfl_xor(ax, 16); ay += __shfl_xor(ay, 16);
  az += __shfl_xor(az, 16); aw += __shfl_xor(aw, 16);
  ax += __shfl_xor(ax, 32); ay += __shfl_xor(ay, 32);
  az += __shfl_xor(az, 32); aw += __shfl_xor(aw, 32);
  // h2 chunk = relu(agg + self*sc + b2)
  float sc = isd * isd;
  float4 self = *(const float4*)(hraw + (size_t)wid * 64 + fl * 4);
  float4 bb   = *(const float4*)(b2 + fl * 4);
  float hx = fmaxf(ax + self.x * sc + bb.x, 0.f);
  float hy = fmaxf(ay + self.y * sc + bb.y, 0.f);
  float hz = fmaxf(az + self.z * sc + bb.z, 0.f);
  float hw = fmaxf(aw + self.w * sc + bb.w, 0.f);
  // h3 = h2 @ W3  (partial per lane, reduce within 16-lane group)
  float p0 = hx * w30[0] + hy * w30[1] + hz * w30[2] + hw * w30[3];
  float p1 = hx * w31[0] + hy * w31[1] + hz * w31[2] + hw * w31[3];
#pragma unroll
  for (int d = 8; d; d >>= 1) { p0 += __shfl_xor(p0, d); p1 += __shfl_xor(p1, d); }
  if (lane == 0) {
    h3[(size_t)wid * 2]     = p0;
    h3[(size_t)wid * 2 + 1] = p1;
  }
}

// out = A_norm @ h3 + self + b3
__global__ void k_agg2(const float* __restrict__ h3, const int* __restrict__ offs,
                       const int* __restrict__ srcs, const float* __restrict__ inv_sqrt,
                       const float* __restrict__ b3, float* __restrict__ out, int n) {
  int wid = (blockIdx.x * blockDim.x + threadIdx.x) >> 6;
  int lane = threadIdx.x & 63;
  if (wid >= n) return;
  int beg = offs[wid], end = offs[wid + 1];
  float isd = inv_sqrt[wid];
  float a0 = 0.f, a1 = 0.f;
  for (int j = beg + lane; j < end; j += 64) {
    int s = srcs[j];
    float c = inv_sqrt[s] * isd;
    a0 = fmaf(h3[(size_t)s * 2], c, a0);
    a1 = fmaf(h3[(size_t)s * 2 + 1], c, a1);
  }
#pragma unroll
  for (int d = 32; d; d >>= 1) { a0 += __shfl_xor(a0, d); a1 += __shfl_xor(a1, d); }
  if (lane == 0) {
    float sc = isd * isd;
    out[(size_t)wid * 2]     = a0 + h3[(size_t)wid * 2] * sc + b3[0];
    out[(size_t)wid * 2 + 1] = a1 + h3[(size_t)wid * 2 + 1] * sc + b3[1];
  }
}

// ---------------- launcher ----------------

extern "C" void kernel_launch(void* const* d_in, const int* in_sizes, int n_in,
                              void* d_out, int out_size, void* d_ws, size_t ws_size,
                              hipStream_t stream) {
  const float* x  = (const float*)d_in[0];
  const int*   ei = (const int*)d_in[1];
  const float* W1 = (const float*)d_in[2];
  const float* b1 = (const float*)d_in[3];
  const float* W2 = (const float*)d_in[4];
  const float* b2 = (const float*)d_in[5];
  const float* W3 = (const float*)d_in[6];
  const float* b3 = (const float*)d_in[7];
  float* out = (float*)d_out;

  const int N = in_sizes[0] / 5;
  const int E = in_sizes[1] / 2;
  const int* src = ei;
  const int* dst = ei + E;

  const int NB = (N + 255) >> 8;
  const int chunk = (E + CB - 1) / CB;
  const int n2 = NB * CB;
  const int nb2 = (n2 + 1023) / 1024;

  char* p = (char*)d_ws;
  auto alloc = [&](size_t bytes) {
    char* r = p;
    p += (bytes + 255) & ~(size_t)255;
    return r;
  };
  int*      histG     = (int*)alloc((size_t)n2 * 4);
  int*      histS     = (int*)alloc((size_t)n2 * 4);
  int*      blockSums = (int*)alloc((size_t)nb2 * 4);
  int*      blockOffs = (int*)alloc((size_t)(nb2 + 1) * 4);
  unsigned* recs      = (unsigned*)alloc((size_t)E * 4);
  int*      srcs      = (int*)alloc((size_t)E * 4);
  int*      offs      = (int*)alloc((size_t)(N + 1) * 4);
  float*    inv_sqrt  = (float*)alloc((size_t)N * 4);
  float*    h1        = (float*)alloc((size_t)N * 64 * 4);
  float*    hB        = (float*)alloc((size_t)N * 64 * 4);
  float*    h3        = (float*)alloc((size_t)N * 2 * 4);

  const int wavesBlocks = (N * 64 + 255) / 256;  // one wave per node

  // CSR build via stable bucket sort — zero global atomics
  k_hist<<<CB, 256, 0, stream>>>(dst, histG, E, NB, chunk);
  k_scan_local<<<nb2, 1024, 0, stream>>>(histG, histS, blockSums, n2);
  k_scan_blocks<<<1, 64, 0, stream>>>(blockSums, blockOffs, nb2);
  k_scan_addg<<<nb2, 1024, 0, stream>>>(histS, blockOffs, n2);
  k_scatter<<<CB, 256, 0, stream>>>(src, dst, histS, recs, E, NB, chunk);
  k_build<<<NB, 256, 0, stream>>>(recs, histS, offs, inv_sqrt, srcs, N, NB, E);

  // layer 1 (agg + W1 + relu fused)
  k_agg5l1<<<wavesBlocks, 256, 0, stream>>>(x, offs, srcs, inv_sqrt, W1, b1, h1, N);
  // layer 2 projection
  k_hw2<<<2048, 256, 0, stream>>>(h1, W2, hB, N);
  // layers 2+3 fused: agg + b2 + relu + W3
  k_agg64w3<<<wavesBlocks, 256, 0, stream>>>(hB, offs, srcs, inv_sqrt, b2, W3, h3, N);
  // layer 3 aggregation
  k_agg2<<<wavesBlocks, 256, 0, stream>>>(h3, offs, srcs, inv_sqrt, b3, out, N);
}

// Round 6
// 275.635 us; speedup vs baseline: 3.0119x; 1.0637x over previous
//
#include <hip/hip_runtime.h>

#define CB 256        // chunk-blocks for hist/scatter
#define MAXNB 1024    // max buckets (N <= 262144)

// ---------------- bucket-sort CSR build (no global atomics) ----------------

__global__ void k_hist(const int* __restrict__ dst, int* __restrict__ histG,
                       int E, int NB, int chunk) {
  __shared__ int hist[MAXNB];
  int b = blockIdx.x, tid = threadIdx.x;
  for (int k = tid; k < NB; k += 256) hist[k] = 0;
  __syncthreads();
  int beg = b * chunk, end = min(E, beg + chunk);
  for (int i = beg + tid; i < end; i += 256) atomicAdd(&hist[dst[i] >> 8], 1);
  __syncthreads();
  for (int k = tid; k < NB; k += 256) histG[(size_t)k * CB + b] = hist[k];
}

__global__ void k_scan_local(const int* __restrict__ in, int* __restrict__ out,
                             int* __restrict__ blockSums, int n) {
  __shared__ int wsum[16];
  __shared__ int wpre[16];
  int tid = threadIdx.x;
  int gid = blockIdx.x * 1024 + tid;
  int v = (gid < n) ? in[gid] : 0;
  int lane = tid & 63, wv = tid >> 6;
  int x = v;
#pragma unroll
  for (int d = 1; d < 64; d <<= 1) {
    int t = __shfl_up(x, d);
    if (lane >= d) x += t;
  }
  if (lane == 63) wsum[wv] = x;
  __syncthreads();
  if (tid == 0) {
    int run = 0;
#pragma unroll
    for (int i = 0; i < 16; ++i) { wpre[i] = run; run += wsum[i]; }
    blockSums[blockIdx.x] = run;
  }
  __syncthreads();
  if (gid < n) out[gid] = x - v + wpre[wv];
}

__global__ void k_scan_blocks(const int* __restrict__ blockSums, int* __restrict__ blockOffs, int nb) {
  if (threadIdx.x == 0 && blockIdx.x == 0) {
    int run = 0;
    for (int i = 0; i < nb; ++i) { blockOffs[i] = run; run += blockSums[i]; }
    blockOffs[nb] = run;
  }
}

__global__ void k_scan_addg(int* __restrict__ data, const int* __restrict__ blockOffs, int n) {
  int gid = blockIdx.x * 1024 + threadIdx.x;
  if (gid < n) data[gid] += blockOffs[blockIdx.x];
}

__global__ void k_scatter(const int* __restrict__ src, const int* __restrict__ dst,
                          const int* __restrict__ histS, unsigned* __restrict__ recs,
                          int E, int NB, int chunk) {
  __shared__ int cur[MAXNB];
  int b = blockIdx.x, tid = threadIdx.x;
  for (int k = tid; k < NB; k += 256) cur[k] = histS[(size_t)k * CB + b];
  __syncthreads();
  int beg = b * chunk, end = min(E, beg + chunk);
  for (int i = beg + tid; i < end; i += 256) {
    int s = src[i], d = dst[i];
    int pos = atomicAdd(&cur[d >> 8], 1);
    recs[pos] = ((unsigned)s << 8) | (unsigned)(d & 255);
  }
}

__global__ void k_build(const unsigned* __restrict__ recs, const int* __restrict__ histS,
                        int* __restrict__ offs, float* __restrict__ inv_sqrt,
                        int* __restrict__ srcs, int N, int NB, int E) {
  __shared__ int cnt[256];
  __shared__ int cur[256];
  __shared__ int wtot[4];
  int k = blockIdx.x, tid = threadIdx.x;
  int ebeg = histS[(size_t)k * CB];
  int eend = (k + 1 < NB) ? histS[(size_t)(k + 1) * CB] : E;
  cnt[tid] = 0;
  __syncthreads();
  for (int i = ebeg + tid; i < eend; i += 256) atomicAdd(&cnt[recs[i] & 255u], 1);
  __syncthreads();
  int v = cnt[tid];
  int lane = tid & 63, w = tid >> 6;
  int x = v;
#pragma unroll
  for (int d = 1; d < 64; d <<= 1) {
    int t = __shfl_up(x, d);
    if (lane >= d) x += t;
  }
  if (lane == 63) wtot[w] = x;
  __syncthreads();
  int pre = 0;
  for (int i = 0; i < w; ++i) pre += wtot[i];
  int gpos = ebeg + (x - v) + pre;
  int node = k * 256 + tid;
  if (node < N) {
    offs[node] = gpos;
    inv_sqrt[node] = rsqrtf(1.0f + (float)v);
  }
  cur[tid] = gpos;
  if (k == NB - 1 && tid == 0) offs[N] = E;
  __syncthreads();
  for (int i = ebeg + tid; i < eend; i += 256) {
    unsigned r = recs[i];
    int pos = atomicAdd(&cur[r & 255u], 1);
    srcs[pos] = (int)(r >> 8);
  }
}

// ---------------- layer kernels ----------------

// layers 1+2a fused: h1 = relu((A_norm x) W1 + b1); h2raw = h1 @ W2
// Grid-stride waves; W1 frag + W2 column in VGPRs; h1 row staged in wave-private
// LDS slot for the broadcast GEMV. h1 never touches global memory.
__global__ void k_l12(const float* __restrict__ x, const int* __restrict__ offs,
                      const int* __restrict__ srcs, const float* __restrict__ inv_sqrt,
                      const float* __restrict__ W1, const float* __restrict__ b1,
                      const float* __restrict__ W2, float* __restrict__ h2raw, int n) {
  __shared__ float hrow[4 * 64];
  int tid = threadIdx.x;
  int lane = tid & 63, w = tid >> 6;
  float w1r[5];
#pragma unroll
  for (int k = 0; k < 5; ++k) w1r[k] = W1[k * 64 + lane];
  float bias = b1[lane];
  float wreg[64];
#pragma unroll
  for (int k = 0; k < 64; ++k) wreg[k] = W2[k * 64 + lane];
  float* slot = &hrow[w * 64];
  int wid0 = (blockIdx.x * blockDim.x + tid) >> 6;
  int nw = (gridDim.x * blockDim.x) >> 6;
  for (int i = wid0; i < n; i += nw) {
    int beg = offs[i], end = offs[i + 1];
    float isd = inv_sqrt[i];
    float a0 = 0.f, a1 = 0.f, a2 = 0.f, a3 = 0.f, a4 = 0.f;
    for (int j = beg + lane; j < end; j += 64) {
      int s = srcs[j];
      float c = inv_sqrt[s] * isd;
      const float* xs = x + (size_t)s * 5;
      a0 = fmaf(xs[0], c, a0); a1 = fmaf(xs[1], c, a1); a2 = fmaf(xs[2], c, a2);
      a3 = fmaf(xs[3], c, a3); a4 = fmaf(xs[4], c, a4);
    }
#pragma unroll
    for (int d = 32; d; d >>= 1) {
      a0 += __shfl_xor(a0, d); a1 += __shfl_xor(a1, d); a2 += __shfl_xor(a2, d);
      a3 += __shfl_xor(a3, d); a4 += __shfl_xor(a4, d);
    }
    float sc = isd * isd;
    const float* xi = x + (size_t)i * 5;
    a0 = fmaf(xi[0], sc, a0); a1 = fmaf(xi[1], sc, a1); a2 = fmaf(xi[2], sc, a2);
    a3 = fmaf(xi[3], sc, a3); a4 = fmaf(xi[4], sc, a4);
    float h1v = bias;
    h1v = fmaf(a0, w1r[0], h1v); h1v = fmaf(a1, w1r[1], h1v); h1v = fmaf(a2, w1r[2], h1v);
    h1v = fmaf(a3, w1r[3], h1v); h1v = fmaf(a4, w1r[4], h1v);
    h1v = fmaxf(h1v, 0.f);
    slot[lane] = h1v;                         // wave-private; DS pipe in-order per wave
    float acc0 = 0.f, acc1 = 0.f, acc2 = 0.f, acc3 = 0.f;
#pragma unroll
    for (int k4 = 0; k4 < 16; ++k4) {
      float4 hq = *(const float4*)&slot[k4 * 4];  // same addr all lanes -> broadcast
      acc0 = fmaf(hq.x, wreg[k4 * 4],     acc0);
      acc1 = fmaf(hq.y, wreg[k4 * 4 + 1], acc1);
      acc2 = fmaf(hq.z, wreg[k4 * 4 + 2], acc2);
      acc3 = fmaf(hq.w, wreg[k4 * 4 + 3], acc3);
    }
    h2raw[(size_t)i * 64 + lane] = (acc0 + acc1) + (acc2 + acc3);
  }
}

// layers 2b+3a fused: h2 = relu(A_norm @ h2raw + b2); h3 = h2 @ W3
// 4 edge slots x 4-deep unroll = 16 independent row-gathers in flight per wave.
__global__ void k_agg64w3(const float* __restrict__ hraw, const int* __restrict__ offs,
                          const int* __restrict__ srcs, const float* __restrict__ inv_sqrt,
                          const float* __restrict__ b2, const float* __restrict__ W3,
                          float* __restrict__ h3, int n) {
  int wid = (blockIdx.x * blockDim.x + threadIdx.x) >> 6;
  int lane = threadIdx.x & 63;
  if (wid >= n) return;
  int sub = lane >> 4;
  int fl  = lane & 15;
  float w30[4], w31[4];
#pragma unroll
  for (int q = 0; q < 4; ++q) {
    w30[q] = W3[(fl * 4 + q) * 2];
    w31[q] = W3[(fl * 4 + q) * 2 + 1];
  }
  int beg = offs[wid], end = offs[wid + 1];
  float isd = inv_sqrt[wid];
  float ax0 = 0.f, ay0 = 0.f, az0 = 0.f, aw0 = 0.f;
  float ax1 = 0.f, ay1 = 0.f, az1 = 0.f, aw1 = 0.f;
  int j = beg + sub;
  // main: 4 edges per sub-slot per iteration -> 16 row-loads in flight per wave
  for (; j + 12 < end; j += 16) {
    int s0 = srcs[j], s1 = srcs[j + 4], s2 = srcs[j + 8], s3 = srcs[j + 12];
    float c0 = inv_sqrt[s0] * isd, c1 = inv_sqrt[s1] * isd;
    float c2 = inv_sqrt[s2] * isd, c3 = inv_sqrt[s3] * isd;
    float4 r0 = *(const float4*)(hraw + (size_t)s0 * 64 + fl * 4);
    float4 r1 = *(const float4*)(hraw + (size_t)s1 * 64 + fl * 4);
    float4 r2 = *(const float4*)(hraw + (size_t)s2 * 64 + fl * 4);
    float4 r3 = *(const float4*)(hraw + (size_t)s3 * 64 + fl * 4);
    ax0 = fmaf(r0.x, c0, ax0); ay0 = fmaf(r0.y, c0, ay0);
    az0 = fmaf(r0.z, c0, az0); aw0 = fmaf(r0.w, c0, aw0);
    ax1 = fmaf(r1.x, c1, ax1); ay1 = fmaf(r1.y, c1, ay1);
    az1 = fmaf(r1.z, c1, az1); aw1 = fmaf(r1.w, c1, aw1);
    ax0 = fmaf(r2.x, c2, ax0); ay0 = fmaf(r2.y, c2, ay0);
    az0 = fmaf(r2.z, c2, az0); aw0 = fmaf(r2.w, c2, aw0);
    ax1 = fmaf(r3.x, c3, ax1); ay1 = fmaf(r3.y, c3, ay1);
    az1 = fmaf(r3.z, c3, az1); aw1 = fmaf(r3.w, c3, aw1);
  }
  for (; j < end; j += 4) {
    int s0 = srcs[j];
    float c0 = inv_sqrt[s0] * isd;
    float4 r0 = *(const float4*)(hraw + (size_t)s0 * 64 + fl * 4);
    ax0 = fmaf(r0.x, c0, ax0); ay0 = fmaf(r0.y, c0, ay0);
    az0 = fmaf(r0.z, c0, az0); aw0 = fmaf(r0.w, c0, aw0);
  }
  float ax = ax0 + ax1, ay = ay0 + ay1, az = az0 + az1, aw = aw0 + aw1;
  ax += __shfl_xor(ax, 16); ay += __shfl_xor(ay, 16);
  az += __shfl_xor(az, 16); aw += __shfl_xor(aw, 16);
  ax += __shfl_xor(ax, 32); ay += __shfl_xor(ay, 32);
  az += __shfl_xor(az, 32); aw += __shfl_xor(aw, 32);
  float sc = isd * isd;
  float4 self = *(const float4*)(hraw + (size_t)wid * 64 + fl * 4);
  float4 bb   = *(const float4*)(b2 + fl * 4);
  float hx = fmaxf(ax + self.x * sc + bb.x, 0.f);
  float hy = fmaxf(ay + self.y * sc + bb.y, 0.f);
  float hz = fmaxf(az + self.z * sc + bb.z, 0.f);
  float hw = fmaxf(aw + self.w * sc + bb.w, 0.f);
  float p0 = hx * w30[0] + hy * w30[1] + hz * w30[2] + hw * w30[3];
  float p1 = hx * w31[0] + hy * w31[1] + hz * w31[2] + hw * w31[3];
#pragma unroll
  for (int d = 8; d; d >>= 1) { p0 += __shfl_xor(p0, d); p1 += __shfl_xor(p1, d); }
  if (lane == 0) {
    h3[(size_t)wid * 2]     = p0;
    h3[(size_t)wid * 2 + 1] = p1;
  }
}

// out = A_norm @ h3 + self + b3
__global__ void k_agg2(const float* __restrict__ h3, const int* __restrict__ offs,
                       const int* __restrict__ srcs, const float* __restrict__ inv_sqrt,
                       const float* __restrict__ b3, float* __restrict__ out, int n) {
  int wid = (blockIdx.x * blockDim.x + threadIdx.x) >> 6;
  int lane = threadIdx.x & 63;
  if (wid >= n) return;
  int beg = offs[wid], end = offs[wid + 1];
  float isd = inv_sqrt[wid];
  float a0 = 0.f, a1 = 0.f;
  for (int j = beg + lane; j < end; j += 64) {
    int s = srcs[j];
    float c = inv_sqrt[s] * isd;
    a0 = fmaf(h3[(size_t)s * 2], c, a0);
    a1 = fmaf(h3[(size_t)s * 2 + 1], c, a1);
  }
#pragma unroll
  for (int d = 32; d; d >>= 1) { a0 += __shfl_xor(a0, d); a1 += __shfl_xor(a1, d); }
  if (lane == 0) {
    float sc = isd * isd;
    out[(size_t)wid * 2]     = a0 + h3[(size_t)wid * 2] * sc + b3[0];
    out[(size_t)wid * 2 + 1] = a1 + h3[(size_t)wid * 2 + 1] * sc + b3[1];
  }
}

// ---------------- launcher ----------------

extern "C" void kernel_launch(void* const* d_in, const int* in_sizes, int n_in,
                              void* d_out, int out_size, void* d_ws, size_t ws_size,
                              hipStream_t stream) {
  const float* x  = (const float*)d_in[0];
  const int*   ei = (const int*)d_in[1];
  const float* W1 = (const float*)d_in[2];
  const float* b1 = (const float*)d_in[3];
  const float* W2 = (const float*)d_in[4];
  const float* b2 = (const float*)d_in[5];
  const float* W3 = (const float*)d_in[6];
  const float* b3 = (const float*)d_in[7];
  float* out = (float*)d_out;

  const int N = in_sizes[0] / 5;
  const int E = in_sizes[1] / 2;
  const int* src = ei;
  const int* dst = ei + E;

  const int NB = (N + 255) >> 8;
  const int chunk = (E + CB - 1) / CB;
  const int n2 = NB * CB;
  const int nb2 = (n2 + 1023) / 1024;

  char* p = (char*)d_ws;
  auto alloc = [&](size_t bytes) {
    char* r = p;
    p += (bytes + 255) & ~(size_t)255;
    return r;
  };
  int*      histG     = (int*)alloc((size_t)n2 * 4);
  int*      histS     = (int*)alloc((size_t)n2 * 4);
  int*      blockSums = (int*)alloc((size_t)nb2 * 4);
  int*      blockOffs = (int*)alloc((size_t)(nb2 + 1) * 4);
  unsigned* recs      = (unsigned*)alloc((size_t)E * 4);
  int*      srcs      = (int*)alloc((size_t)E * 4);
  int*      offs      = (int*)alloc((size_t)(N + 1) * 4);
  float*    inv_sqrt  = (float*)alloc((size_t)N * 4);
  float*    hB        = (float*)alloc((size_t)N * 64 * 4);
  float*    h3        = (float*)alloc((size_t)N * 2 * 4);

  const int wavesBlocks = (N * 64 + 255) / 256;  // one wave per node

  // CSR build via stable bucket sort — zero global atomics
  k_hist<<<CB, 256, 0, stream>>>(dst, histG, E, NB, chunk);
  k_scan_local<<<nb2, 1024, 0, stream>>>(histG, histS, blockSums, n2);
  k_scan_blocks<<<1, 64, 0, stream>>>(blockSums, blockOffs, nb2);
  k_scan_addg<<<nb2, 1024, 0, stream>>>(histS, blockOffs, n2);
  k_scatter<<<CB, 256, 0, stream>>>(src, dst, histS, recs, E, NB, chunk);
  k_build<<<NB, 256, 0, stream>>>(recs, histS, offs, inv_sqrt, srcs, N, NB, E);

  // layers 1+2a fused: h2raw = relu((A x) W1 + b1) @ W2  (h1 stays on-chip)
  k_l12<<<2048, 256, 0, stream>>>(x, offs, srcs, inv_sqrt, W1, b1, W2, hB, N);
  // layers 2b+3a fused: h3 = relu(A_norm h2raw + b2) @ W3
  k_agg64w3<<<wavesBlocks, 256, 0, stream>>>(hB, offs, srcs, inv_sqrt, b2, W3, h3, N);
  // layer 3 aggregation
  k_agg2<<<wavesBlocks, 256, 0, stream>>>(h3, offs, srcs, inv_sqrt, b3, out, N);
}

// Round 7
// 263.744 us; speedup vs baseline: 3.1477x; 1.0451x over previous
//
#include <hip/hip_runtime.h>

#define CB 256        // chunk-blocks for hist/scatter
#define MAXNB 1024    // max buckets (N <= 262144)

// ---------------- bucket-sort CSR build (no global atomics) ----------------

__global__ void k_hist(const int* __restrict__ dst, int* __restrict__ histG,
                       int E, int NB, int chunk) {
  __shared__ int hist[MAXNB];
  int b = blockIdx.x, tid = threadIdx.x;
  for (int k = tid; k < NB; k += 256) hist[k] = 0;
  __syncthreads();
  int beg = b * chunk, end = min(E, beg + chunk);
  for (int i = beg + tid; i < end; i += 256) atomicAdd(&hist[dst[i] >> 8], 1);
  __syncthreads();
  for (int k = tid; k < NB; k += 256) histG[(size_t)k * CB + b] = hist[k];
}

__global__ void k_scan_local(const int* __restrict__ in, int* __restrict__ out,
                             int* __restrict__ blockSums, int n) {
  __shared__ int wsum[16];
  __shared__ int wpre[16];
  int tid = threadIdx.x;
  int gid = blockIdx.x * 1024 + tid;
  int v = (gid < n) ? in[gid] : 0;
  int lane = tid & 63, wv = tid >> 6;
  int x = v;
#pragma unroll
  for (int d = 1; d < 64; d <<= 1) {
    int t = __shfl_up(x, d);
    if (lane >= d) x += t;
  }
  if (lane == 63) wsum[wv] = x;
  __syncthreads();
  if (tid == 0) {
    int run = 0;
#pragma unroll
    for (int i = 0; i < 16; ++i) { wpre[i] = run; run += wsum[i]; }
    blockSums[blockIdx.x] = run;
  }
  __syncthreads();
  if (gid < n) out[gid] = x - v + wpre[wv];
}

// parallel scan of block sums (single block, 256 threads, nb <= 256)
__global__ void k_scan_blocks(const int* __restrict__ blockSums, int* __restrict__ blockOffs, int nb) {
  __shared__ int wtot[4];
  int tid = threadIdx.x;
  int lane = tid & 63, w = tid >> 6;
  int v = (tid < nb) ? blockSums[tid] : 0;
  int x = v;
#pragma unroll
  for (int d = 1; d < 64; d <<= 1) {
    int t = __shfl_up(x, d);
    if (lane >= d) x += t;
  }
  if (lane == 63) wtot[w] = x;
  __syncthreads();
  int pre = 0;
  for (int i = 0; i < w; ++i) pre += wtot[i];
  int ex = x - v + pre;            // exclusive prefix
  if (tid < nb) blockOffs[tid] = ex;
  if (tid == nb - 1) blockOffs[nb] = ex + v;  // total
}

// stable scatter; per-(bucket,block) base = histS (block-local scan) + blockOffs fused
__global__ void k_scatter(const int* __restrict__ src, const int* __restrict__ dst,
                          const int* __restrict__ histS, const int* __restrict__ blockOffs,
                          unsigned* __restrict__ recs, int E, int NB, int chunk) {
  __shared__ int cur[MAXNB];
  int b = blockIdx.x, tid = threadIdx.x;
  for (int k = tid; k < NB; k += 256) {
    int gid = k * CB + b;
    cur[k] = histS[gid] + blockOffs[gid >> 10];
  }
  __syncthreads();
  int beg = b * chunk, end = min(E, beg + chunk);
  for (int i = beg + tid; i < end; i += 256) {
    int s = src[i], d = dst[i];
    int pos = atomicAdd(&cur[d >> 8], 1);
    recs[pos] = ((unsigned)s << 8) | (unsigned)(d & 255);
  }
}

__global__ void k_build(const unsigned* __restrict__ recs, const int* __restrict__ histS,
                        const int* __restrict__ blockOffs,
                        int* __restrict__ offs, float* __restrict__ inv_sqrt,
                        int* __restrict__ srcs, int N, int NB, int E) {
  __shared__ int cnt[256];
  __shared__ int cur[256];
  __shared__ int wtot[4];
  int k = blockIdx.x, tid = threadIdx.x;
  int g0 = k * CB;
  int ebeg = histS[g0] + blockOffs[g0 >> 10];
  int eend = E;
  if (k + 1 < NB) {
    int g1 = (k + 1) * CB;
    eend = histS[g1] + blockOffs[g1 >> 10];
  }
  cnt[tid] = 0;
  __syncthreads();
  for (int i = ebeg + tid; i < eend; i += 256) atomicAdd(&cnt[recs[i] & 255u], 1);
  __syncthreads();
  int v = cnt[tid];
  int lane = tid & 63, w = tid >> 6;
  int x = v;
#pragma unroll
  for (int d = 1; d < 64; d <<= 1) {
    int t = __shfl_up(x, d);
    if (lane >= d) x += t;
  }
  if (lane == 63) wtot[w] = x;
  __syncthreads();
  int pre = 0;
  for (int i = 0; i < w; ++i) pre += wtot[i];
  int gpos = ebeg + (x - v) + pre;
  int node = k * 256 + tid;
  if (node < N) {
    offs[node] = gpos;
    inv_sqrt[node] = rsqrtf(1.0f + (float)v);
  }
  cur[tid] = gpos;
  if (k == NB - 1 && tid == 0) offs[N] = E;
  __syncthreads();
  for (int i = ebeg + tid; i < eend; i += 256) {
    unsigned r = recs[i];
    int pos = atomicAdd(&cur[r & 255u], 1);
    srcs[pos] = (int)(r >> 8);
  }
}

// ---------------- layer kernels ----------------

// layers 1+2a fused, TWO nodes per wave:
//  lanes 0-31 aggregate node iA's edges, lanes 32-63 node iB's (5-level reduce,
//  25 swizzles for 2 nodes vs 30/node before), cross-copy via 10 shfls, then
//  both 64-wide GEMVs h1 -> h2raw run on the full wave with W2 in VGPRs.
__global__ void k_l12(const float* __restrict__ x, const int* __restrict__ offs,
                      const int* __restrict__ srcs, const float* __restrict__ inv_sqrt,
                      const float* __restrict__ W1, const float* __restrict__ b1,
                      const float* __restrict__ W2, float* __restrict__ h2raw, int n) {
  __shared__ float hrow[4][2][64];
  int tid = threadIdx.x;
  int lane = tid & 63, w = tid >> 6;
  int hl = lane & 31, half = lane >> 5;
  float w1r[5];
#pragma unroll
  for (int k = 0; k < 5; ++k) w1r[k] = W1[k * 64 + lane];
  float bias = b1[lane];
  float wreg[64];
#pragma unroll
  for (int k = 0; k < 64; ++k) wreg[k] = W2[k * 64 + lane];
  float* slotA = &hrow[w][0][0];
  float* slotB = &hrow[w][1][0];
  int wid0 = (blockIdx.x * blockDim.x + tid) >> 6;
  int nw = (gridDim.x * blockDim.x) >> 6;
  for (int i2 = wid0 * 2; i2 < n; i2 += nw * 2) {
    int iA = i2, iB = i2 + 1;
    int node = (half == 0) ? iA : iB;
    bool valid = node < n;
    float a0 = 0.f, a1 = 0.f, a2 = 0.f, a3 = 0.f, a4 = 0.f;
    float isd = 0.f;
    if (valid) {
      isd = inv_sqrt[node];
      int beg = offs[node], end = offs[node + 1];
      for (int j = beg + hl; j < end; j += 32) {
        int s = srcs[j];
        float c = inv_sqrt[s] * isd;
        const float* xs = x + (size_t)s * 5;
        float4 xv = *(const float4*)xs;    // 4B-aligned dwordx4 (HW-legal)
        float x4 = xs[4];
        a0 = fmaf(xv.x, c, a0); a1 = fmaf(xv.y, c, a1); a2 = fmaf(xv.z, c, a2);
        a3 = fmaf(xv.w, c, a3); a4 = fmaf(x4, c, a4);
      }
    }
    // reduce within each 32-lane half
#pragma unroll
    for (int d = 16; d; d >>= 1) {
      a0 += __shfl_xor(a0, d); a1 += __shfl_xor(a1, d); a2 += __shfl_xor(a2, d);
      a3 += __shfl_xor(a3, d); a4 += __shfl_xor(a4, d);
    }
    // self term (per half, wave-uniform loads)
    if (valid) {
      float sc = isd * isd;
      const float* xi = x + (size_t)node * 5;
      a0 = fmaf(xi[0], sc, a0); a1 = fmaf(xi[1], sc, a1); a2 = fmaf(xi[2], sc, a2);
      a3 = fmaf(xi[3], sc, a3); a4 = fmaf(xi[4], sc, a4);
    }
    // cross-copy: all lanes get node A's sums and node B's sums
    float aA0 = __shfl(a0, hl),      aA1 = __shfl(a1, hl),      aA2 = __shfl(a2, hl);
    float aA3 = __shfl(a3, hl),      aA4 = __shfl(a4, hl);
    float aB0 = __shfl(a0, hl | 32), aB1 = __shfl(a1, hl | 32), aB2 = __shfl(a2, hl | 32);
    float aB3 = __shfl(a3, hl | 32), aB4 = __shfl(a4, hl | 32);
    // h1 for both nodes (lane = output feature)
    float hA = bias;
    hA = fmaf(aA0, w1r[0], hA); hA = fmaf(aA1, w1r[1], hA); hA = fmaf(aA2, w1r[2], hA);
    hA = fmaf(aA3, w1r[3], hA); hA = fmaf(aA4, w1r[4], hA);
    hA = fmaxf(hA, 0.f);
    float hB = bias;
    hB = fmaf(aB0, w1r[0], hB); hB = fmaf(aB1, w1r[1], hB); hB = fmaf(aB2, w1r[2], hB);
    hB = fmaf(aB3, w1r[3], hB); hB = fmaf(aB4, w1r[4], hB);
    hB = fmaxf(hB, 0.f);
    slotA[lane] = hA;
    slotB[lane] = hB;
    // GEMV A (broadcast b128 reads; wave-private slot, in-order DS pipe)
    float ac0 = 0.f, ac1 = 0.f, ac2 = 0.f, ac3 = 0.f;
#pragma unroll
    for (int k4 = 0; k4 < 16; ++k4) {
      float4 hq = *(const float4*)&slotA[k4 * 4];
      ac0 = fmaf(hq.x, wreg[k4 * 4],     ac0);
      ac1 = fmaf(hq.y, wreg[k4 * 4 + 1], ac1);
      ac2 = fmaf(hq.z, wreg[k4 * 4 + 2], ac2);
      ac3 = fmaf(hq.w, wreg[k4 * 4 + 3], ac3);
    }
    h2raw[(size_t)iA * 64 + lane] = (ac0 + ac1) + (ac2 + ac3);
    if (iB < n) {
      float bc0 = 0.f, bc1 = 0.f, bc2 = 0.f, bc3 = 0.f;
#pragma unroll
      for (int k4 = 0; k4 < 16; ++k4) {
        float4 hq = *(const float4*)&slotB[k4 * 4];
        bc0 = fmaf(hq.x, wreg[k4 * 4],     bc0);
        bc1 = fmaf(hq.y, wreg[k4 * 4 + 1], bc1);
        bc2 = fmaf(hq.z, wreg[k4 * 4 + 2], bc2);
        bc3 = fmaf(hq.w, wreg[k4 * 4 + 3], bc3);
      }
      h2raw[(size_t)iB * 64 + lane] = (bc0 + bc1) + (bc2 + bc3);
    }
  }
}

// layers 2b+3a fused: h2 = relu(A_norm @ h2raw + b2); h3 = h2 @ W3
__global__ void k_agg64w3(const float* __restrict__ hraw, const int* __restrict__ offs,
                          const int* __restrict__ srcs, const float* __restrict__ inv_sqrt,
                          const float* __restrict__ b2, const float* __restrict__ W3,
                          float* __restrict__ h3, int n) {
  int wid = (blockIdx.x * blockDim.x + threadIdx.x) >> 6;
  int lane = threadIdx.x & 63;
  if (wid >= n) return;
  int sub = lane >> 4;
  int fl  = lane & 15;
  float w30[4], w31[4];
#pragma unroll
  for (int q = 0; q < 4; ++q) {
    w30[q] = W3[(fl * 4 + q) * 2];
    w31[q] = W3[(fl * 4 + q) * 2 + 1];
  }
  int beg = offs[wid], end = offs[wid + 1];
  float isd = inv_sqrt[wid];
  float ax0 = 0.f, ay0 = 0.f, az0 = 0.f, aw0 = 0.f;
  float ax1 = 0.f, ay1 = 0.f, az1 = 0.f, aw1 = 0.f;
  int j = beg + sub;
  for (; j + 12 < end; j += 16) {
    int s0 = srcs[j], s1 = srcs[j + 4], s2 = srcs[j + 8], s3 = srcs[j + 12];
    float c0 = inv_sqrt[s0] * isd, c1 = inv_sqrt[s1] * isd;
    float c2 = inv_sqrt[s2] * isd, c3 = inv_sqrt[s3] * isd;
    float4 r0 = *(const float4*)(hraw + (size_t)s0 * 64 + fl * 4);
    float4 r1 = *(const float4*)(hraw + (size_t)s1 * 64 + fl * 4);
    float4 r2 = *(const float4*)(hraw + (size_t)s2 * 64 + fl * 4);
    float4 r3 = *(const float4*)(hraw + (size_t)s3 * 64 + fl * 4);
    ax0 = fmaf(r0.x, c0, ax0); ay0 = fmaf(r0.y, c0, ay0);
    az0 = fmaf(r0.z, c0, az0); aw0 = fmaf(r0.w, c0, aw0);
    ax1 = fmaf(r1.x, c1, ax1); ay1 = fmaf(r1.y, c1, ay1);
    az1 = fmaf(r1.z, c1, az1); aw1 = fmaf(r1.w, c1, aw1);
    ax0 = fmaf(r2.x, c2, ax0); ay0 = fmaf(r2.y, c2, ay0);
    az0 = fmaf(r2.z, c2, az0); aw0 = fmaf(r2.w, c2, aw0);
    ax1 = fmaf(r3.x, c3, ax1); ay1 = fmaf(r3.y, c3, ay1);
    az1 = fmaf(r3.z, c3, az1); aw1 = fmaf(r3.w, c3, aw1);
  }
  for (; j < end; j += 4) {
    int s0 = srcs[j];
    float c0 = inv_sqrt[s0] * isd;
    float4 r0 = *(const float4*)(hraw + (size_t)s0 * 64 + fl * 4);
    ax0 = fmaf(r0.x, c0, ax0); ay0 = fmaf(r0.y, c0, ay0);
    az0 = fmaf(r0.z, c0, az0); aw0 = fmaf(r0.w, c0, aw0);
  }
  float ax = ax0 + ax1, ay = ay0 + ay1, az = az0 + az1, aw = aw0 + aw1;
  ax += __shfl_xor(ax, 16); ay += __shfl_xor(ay, 16);
  az += __shfl_xor(az, 16); aw += __shfl_xor(aw, 16);
  ax += __shfl_xor(ax, 32); ay += __shfl_xor(ay, 32);
  az += __shfl_xor(az, 32); aw += __shfl_xor(aw, 32);
  float sc = isd * isd;
  float4 self = *(const float4*)(hraw + (size_t)wid * 64 + fl * 4);
  float4 bb   = *(const float4*)(b2 + fl * 4);
  float hx = fmaxf(ax + self.x * sc + bb.x, 0.f);
  float hy = fmaxf(ay + self.y * sc + bb.y, 0.f);
  float hz = fmaxf(az + self.z * sc + bb.z, 0.f);
  float hw = fmaxf(aw + self.w * sc + bb.w, 0.f);
  float p0 = hx * w30[0] + hy * w30[1] + hz * w30[2] + hw * w30[3];
  float p1 = hx * w31[0] + hy * w31[1] + hz * w31[2] + hw * w31[3];
#pragma unroll
  for (int d = 8; d; d >>= 1) { p0 += __shfl_xor(p0, d); p1 += __shfl_xor(p1, d); }
  if (lane == 0) {
    h3[(size_t)wid * 2]     = p0;
    h3[(size_t)wid * 2 + 1] = p1;
  }
}

// out = A_norm @ h3 + self + b3
__global__ void k_agg2(const float* __restrict__ h3, const int* __restrict__ offs,
                       const int* __restrict__ srcs, const float* __restrict__ inv_sqrt,
                       const float* __restrict__ b3, float* __restrict__ out, int n) {
  int wid = (blockIdx.x * blockDim.x + threadIdx.x) >> 6;
  int lane = threadIdx.x & 63;
  if (wid >= n) return;
  int beg = offs[wid], end = offs[wid + 1];
  float isd = inv_sqrt[wid];
  float a0 = 0.f, a1 = 0.f;
  for (int j = beg + lane; j < end; j += 64) {
    int s = srcs[j];
    float c = inv_sqrt[s] * isd;
    a0 = fmaf(h3[(size_t)s * 2], c, a0);
    a1 = fmaf(h3[(size_t)s * 2 + 1], c, a1);
  }
#pragma unroll
  for (int d = 32; d; d >>= 1) { a0 += __shfl_xor(a0, d); a1 += __shfl_xor(a1, d); }
  if (lane == 0) {
    float sc = isd * isd;
    out[(size_t)wid * 2]     = a0 + h3[(size_t)wid * 2] * sc + b3[0];
    out[(size_t)wid * 2 + 1] = a1 + h3[(size_t)wid * 2 + 1] * sc + b3[1];
  }
}

// ---------------- launcher ----------------

extern "C" void kernel_launch(void* const* d_in, const int* in_sizes, int n_in,
                              void* d_out, int out_size, void* d_ws, size_t ws_size,
                              hipStream_t stream) {
  const float* x  = (const float*)d_in[0];
  const int*   ei = (const int*)d_in[1];
  const float* W1 = (const float*)d_in[2];
  const float* b1 = (const float*)d_in[3];
  const float* W2 = (const float*)d_in[4];
  const float* b2 = (const float*)d_in[5];
  const float* W3 = (const float*)d_in[6];
  const float* b3 = (const float*)d_in[7];
  float* out = (float*)d_out;

  const int N = in_sizes[0] / 5;
  const int E = in_sizes[1] / 2;
  const int* src = ei;
  const int* dst = ei + E;

  const int NB = (N + 255) >> 8;
  const int chunk = (E + CB - 1) / CB;
  const int n2 = NB * CB;
  const int nb2 = (n2 + 1023) / 1024;   // <= 256

  char* p = (char*)d_ws;
  auto alloc = [&](size_t bytes) {
    char* r = p;
    p += (bytes + 255) & ~(size_t)255;
    return r;
  };
  int*      histG     = (int*)alloc((size_t)n2 * 4);
  int*      histS     = (int*)alloc((size_t)n2 * 4);
  int*      blockSums = (int*)alloc((size_t)nb2 * 4);
  int*      blockOffs = (int*)alloc((size_t)(nb2 + 1) * 4);
  unsigned* recs      = (unsigned*)alloc((size_t)E * 4);
  int*      srcs      = (int*)alloc((size_t)E * 4);
  int*      offs      = (int*)alloc((size_t)(N + 1) * 4);
  float*    inv_sqrt  = (float*)alloc((size_t)N * 4);
  float*    hB        = (float*)alloc((size_t)N * 64 * 4);
  float*    h3        = (float*)alloc((size_t)N * 2 * 4);

  const int wavesBlocks = (N * 64 + 255) / 256;  // one wave per node

  // CSR build via stable bucket sort — zero global atomics
  k_hist<<<CB, 256, 0, stream>>>(dst, histG, E, NB, chunk);
  k_scan_local<<<nb2, 1024, 0, stream>>>(histG, histS, blockSums, n2);
  k_scan_blocks<<<1, 256, 0, stream>>>(blockSums, blockOffs, nb2);
  k_scatter<<<CB, 256, 0, stream>>>(src, dst, histS, blockOffs, recs, E, NB, chunk);
  k_build<<<NB, 256, 0, stream>>>(recs, histS, blockOffs, offs, inv_sqrt, srcs, N, NB, E);

  // layers 1+2a fused (2 nodes per wave): h2raw = relu((A x) W1 + b1) @ W2
  k_l12<<<2048, 256, 0, stream>>>(x, offs, srcs, inv_sqrt, W1, b1, W2, hB, N);
  // layers 2b+3a fused: h3 = relu(A_norm h2raw + b2) @ W3
  k_agg64w3<<<wavesBlocks, 256, 0, stream>>>(hB, offs, srcs, inv_sqrt, b2, W3, h3, N);
  // layer 3 aggregation
  k_agg2<<<wavesBlocks, 256, 0, stream>>>(h3, offs, srcs, inv_sqrt, b3, out, N);
}